// Round 2
// baseline (3263.120 us; speedup 1.0000x reference)
//
#include <hip/hip_runtime.h>

#define N_NODES 100000
#define DIM 128
#define NE 1600000
#define NTILES (N_NODES / 8)   // 12500, exact
#define GEMM_BLOCKS 2048

// ---------------------------------------------------------------------------
// Phase 1: scatter-add x[src] (fp32) into summed[dst] (fp32 ws) + edge counts.
// 32 threads per edge, each handles 4 fp32 features (one 16B load, 4 atomics).
// ---------------------------------------------------------------------------
__global__ __launch_bounds__(256) void scatter_k(const int* __restrict__ ei,
                                                 const float* __restrict__ x,
                                                 float* __restrict__ summed,
                                                 float* __restrict__ cnt) {
  unsigned int tid = blockIdx.x * 256u + threadIdx.x;
  unsigned int e = tid >> 5;
  unsigned int c = tid & 31u;
  if (e >= NE) return;
  int src = ei[e];
  int dst = ei[NE + e];
  float4 v = *(const float4*)(x + (size_t)src * DIM + c * 4);
  float* s = summed + (size_t)dst * DIM + c * 4;
  unsafeAtomicAdd(s + 0, v.x);
  unsafeAtomicAdd(s + 1, v.y);
  unsafeAtomicAdd(s + 2, v.z);
  unsafeAtomicAdd(s + 3, v.w);
  if (c == 0) unsafeAtomicAdd(cnt + dst, 1.0f);
}

// ---------------------------------------------------------------------------
// Phase 2: out = x @ W_r + b_l   (all fp32)
// W_r staged in LDS (64KB). Block = 256 thr: col = t&127, half = t>>7.
// Each half processes 4 rows of an 8-row tile; row loads are wave-uniform
// 16B broadcasts. LDS reads Ws[k*128+c]: 2-way bank alias = free.
// ---------------------------------------------------------------------------
__global__ __launch_bounds__(256) void gemm_xw(const float* __restrict__ x,
                                               const float* __restrict__ W,
                                               const float* __restrict__ b,
                                               float* __restrict__ out) {
  __shared__ float Ws[DIM * DIM];
  for (int i = threadIdx.x; i < DIM * DIM; i += 256) Ws[i] = W[i];
  __syncthreads();
  const int c = threadIdx.x & 127;
  const int half = threadIdx.x >> 7;
  const float bias = b[c];
  for (int tile = blockIdx.x; tile < NTILES; tile += gridDim.x) {
    const int row0 = tile * 8 + half * 4;
    const float* r = x + (size_t)row0 * DIM;
    float a0 = 0.f, a1 = 0.f, a2 = 0.f, a3 = 0.f;
#pragma unroll 8
    for (int k4 = 0; k4 < 32; ++k4) {
      float4 p0 = *(const float4*)(r + 0 * DIM + k4 * 4);
      float4 p1 = *(const float4*)(r + 1 * DIM + k4 * 4);
      float4 p2 = *(const float4*)(r + 2 * DIM + k4 * 4);
      float4 p3 = *(const float4*)(r + 3 * DIM + k4 * 4);
      const float* wp = &Ws[k4 * 4 * DIM + c];
      float w0 = wp[0 * DIM], w1 = wp[1 * DIM], w2 = wp[2 * DIM], w3 = wp[3 * DIM];
      a0 += p0.x * w0 + p0.y * w1 + p0.z * w2 + p0.w * w3;
      a1 += p1.x * w0 + p1.y * w1 + p1.z * w2 + p1.w * w3;
      a2 += p2.x * w0 + p2.y * w1 + p2.z * w2 + p2.w * w3;
      a3 += p3.x * w0 + p3.y * w1 + p3.z * w2 + p3.w * w3;
    }
    out[(size_t)(row0 + 0) * DIM + c] = a0 + bias;
    out[(size_t)(row0 + 1) * DIM + c] = a1 + bias;
    out[(size_t)(row0 + 2) * DIM + c] = a2 + bias;
    out[(size_t)(row0 + 3) * DIM + c] = a3 + bias;
  }
}

// ---------------------------------------------------------------------------
// Phase 3: out += (summed / max(cnt,1)) @ W_l   (all fp32)
// ---------------------------------------------------------------------------
__global__ __launch_bounds__(256) void gemm_aw(const float* __restrict__ summed,
                                               const float* __restrict__ cnt,
                                               const float* __restrict__ W,
                                               float* __restrict__ out) {
  __shared__ float Ws[DIM * DIM];
  for (int i = threadIdx.x; i < DIM * DIM; i += 256) Ws[i] = W[i];
  __syncthreads();
  const int c = threadIdx.x & 127;
  const int half = threadIdx.x >> 7;
  for (int tile = blockIdx.x; tile < NTILES; tile += gridDim.x) {
    const int row0 = tile * 8 + half * 4;
    const float* r = summed + (size_t)row0 * DIM;
    float a0 = 0.f, a1 = 0.f, a2 = 0.f, a3 = 0.f;
#pragma unroll 8
    for (int k4 = 0; k4 < 32; ++k4) {
      float4 p0 = *(const float4*)(r + 0 * DIM + k4 * 4);
      float4 p1 = *(const float4*)(r + 1 * DIM + k4 * 4);
      float4 p2 = *(const float4*)(r + 2 * DIM + k4 * 4);
      float4 p3 = *(const float4*)(r + 3 * DIM + k4 * 4);
      const float* wp = &Ws[k4 * 4 * DIM + c];
      float w0 = wp[0 * DIM], w1 = wp[1 * DIM], w2 = wp[2 * DIM], w3 = wp[3 * DIM];
      a0 += p0.x * w0 + p0.y * w1 + p0.z * w2 + p0.w * w3;
      a1 += p1.x * w0 + p1.y * w1 + p1.z * w2 + p1.w * w3;
      a2 += p2.x * w0 + p2.y * w1 + p2.z * w2 + p2.w * w3;
      a3 += p3.x * w0 + p3.y * w1 + p3.z * w2 + p3.w * w3;
    }
#pragma unroll
    for (int rr = 0; rr < 4; ++rr) {
      float acc = (rr == 0) ? a0 : (rr == 1) ? a1 : (rr == 2) ? a2 : a3;
      float scale = 1.0f / fmaxf(cnt[row0 + rr], 1.0f);
      size_t idx = (size_t)(row0 + rr) * DIM + c;
      out[idx] = out[idx] + scale * acc;
    }
  }
}

extern "C" void kernel_launch(void* const* d_in, const int* in_sizes, int n_in,
                              void* d_out, int out_size, void* d_ws, size_t ws_size,
                              hipStream_t stream) {
  const float* x  = (const float*)d_in[0];
  const int*   ei = (const int*)d_in[1];
  const float* Wl = (const float*)d_in[2];
  const float* bl = (const float*)d_in[3];
  const float* Wr = (const float*)d_in[4];
  float* out = (float*)d_out;

  float* summed = (float*)d_ws;                       // 100000*128 fp32 = 51.2 MB
  float* cnt = summed + (size_t)N_NODES * DIM;        // 100000 fp32 = 0.4 MB

  hipMemsetAsync(d_ws, 0, ((size_t)N_NODES * DIM + N_NODES) * sizeof(float), stream);

  // scatter: 1.6M edges * 32 threads = 51.2M threads
  hipLaunchKernelGGL(scatter_k, dim3((NE * 32) / 256), dim3(256), 0, stream,
                     ei, x, summed, cnt);
  // out = x @ W_r + b_l
  hipLaunchKernelGGL(gemm_xw, dim3(GEMM_BLOCKS), dim3(256), 0, stream,
                     x, Wr, bl, out);
  // out += (summed/cnt) @ W_l
  hipLaunchKernelGGL(gemm_aw, dim3(GEMM_BLOCKS), dim3(256), 0, stream,
                     summed, cnt, Wl, out);
}

// Round 3
// 774.405 us; speedup vs baseline: 4.2137x; 4.2137x over previous
//
#include <hip/hip_runtime.h>

#define N_NODES 100000
#define DIM 128
#define NE 1600000
#define NTILES (N_NODES / 8)   // 12500, exact
#define GEMM_BLOCKS 2048
#define CHUNK 512
#define NCHUNK ((N_NODES + CHUNK - 1) / CHUNK)   // 196

// ===========================================================================
// CSR-build path (no fp32 atomics)
// ===========================================================================

__global__ __launch_bounds__(256) void hist_k(const int* __restrict__ ei,
                                              int* __restrict__ deg) {
  int e = blockIdx.x * 256 + threadIdx.x;
  if (e < NE) atomicAdd(&deg[ei[NE + e]], 1);
}

__global__ __launch_bounds__(512) void scan_sum_k(const int* __restrict__ deg,
                                                  int* __restrict__ partials) {
  __shared__ int s[CHUNK];
  int i = blockIdx.x * CHUNK + threadIdx.x;
  s[threadIdx.x] = (i < N_NODES) ? deg[i] : 0;
  __syncthreads();
  for (int off = 256; off > 0; off >>= 1) {
    if (threadIdx.x < off) s[threadIdx.x] += s[threadIdx.x + off];
    __syncthreads();
  }
  if (threadIdx.x == 0) partials[blockIdx.x] = s[0];
}

__global__ __launch_bounds__(256) void scan_part_k(int* __restrict__ partials) {
  __shared__ int s[256];
  int t = threadIdx.x;
  int v = (t < NCHUNK) ? partials[t] : 0;
  s[t] = v;
  __syncthreads();
  for (int off = 1; off < 256; off <<= 1) {
    int add = (t >= off) ? s[t - off] : 0;
    __syncthreads();
    s[t] += add;
    __syncthreads();
  }
  if (t < NCHUNK) partials[t] = s[t] - v;   // exclusive block bases
}

__global__ __launch_bounds__(512) void scan_out_k(const int* __restrict__ deg,
                                                  const int* __restrict__ partials,
                                                  int* __restrict__ offsets,
                                                  int* __restrict__ cursor) {
  __shared__ int s[CHUNK];
  int t = threadIdx.x;
  int i = blockIdx.x * CHUNK + t;
  int v = (i < N_NODES) ? deg[i] : 0;
  s[t] = v;
  __syncthreads();
  for (int off = 1; off < CHUNK; off <<= 1) {
    int add = (t >= off) ? s[t - off] : 0;
    __syncthreads();
    s[t] += add;
    __syncthreads();
  }
  if (i < N_NODES) {
    int excl = partials[blockIdx.x] + s[t] - v;
    offsets[i] = excl;
    cursor[i] = excl;
  }
  if (i == 0) offsets[N_NODES] = NE;
}

__global__ __launch_bounds__(256) void fill_k(const int* __restrict__ ei,
                                              int* __restrict__ cursor,
                                              int* __restrict__ csr) {
  int e = blockIdx.x * 256 + threadIdx.x;
  if (e < NE) {
    int dst = ei[NE + e];
    int pos = atomicAdd(&cursor[dst], 1);
    csr[pos] = ei[e];
  }
}

// One 64-lane wave per node: lane holds 2 features. csr index is wave-uniform
// (scalar load); each edge row read is 512B coalesced. No atomics.
__global__ __launch_bounds__(256) void agg_k(const int* __restrict__ offsets,
                                             const int* __restrict__ csr,
                                             const float* __restrict__ x,
                                             float* __restrict__ agg) {
  int node = blockIdx.x * 4 + (threadIdx.x >> 6);
  int lane = threadIdx.x & 63;
  int beg = offsets[node], end = offsets[node + 1];
  float ax = 0.f, ay = 0.f;
  int i = beg;
  for (; i + 4 <= end; i += 4) {
    int s0 = csr[i], s1 = csr[i + 1], s2 = csr[i + 2], s3 = csr[i + 3];
    float2 v0 = *(const float2*)(x + (size_t)s0 * DIM + lane * 2);
    float2 v1 = *(const float2*)(x + (size_t)s1 * DIM + lane * 2);
    float2 v2 = *(const float2*)(x + (size_t)s2 * DIM + lane * 2);
    float2 v3 = *(const float2*)(x + (size_t)s3 * DIM + lane * 2);
    ax += v0.x + v1.x + v2.x + v3.x;
    ay += v0.y + v1.y + v2.y + v3.y;
  }
  for (; i < end; ++i) {
    int s0 = csr[i];
    float2 v0 = *(const float2*)(x + (size_t)s0 * DIM + lane * 2);
    ax += v0.x;
    ay += v0.y;
  }
  float scale = 1.0f / fmaxf((float)(end - beg), 1.0f);
  float2 r;
  r.x = ax * scale;
  r.y = ay * scale;
  *(float2*)(agg + (size_t)node * DIM + lane * 2) = r;
}

// ===========================================================================
// Fallback atomic scatter (only if ws too small)
// ===========================================================================
__global__ __launch_bounds__(256) void scatter_k(const int* __restrict__ ei,
                                                 const float* __restrict__ x,
                                                 float* __restrict__ summed,
                                                 float* __restrict__ cnt) {
  unsigned int tid = blockIdx.x * 256u + threadIdx.x;
  unsigned int e = tid >> 5;
  unsigned int c = tid & 31u;
  if (e >= NE) return;
  int src = ei[e];
  int dst = ei[NE + e];
  float4 v = *(const float4*)(x + (size_t)src * DIM + c * 4);
  float* s = summed + (size_t)dst * DIM + c * 4;
  unsafeAtomicAdd(s + 0, v.x);
  unsafeAtomicAdd(s + 1, v.y);
  unsafeAtomicAdd(s + 2, v.z);
  unsafeAtomicAdd(s + 3, v.w);
  if (c == 0) unsafeAtomicAdd(cnt + dst, 1.0f);
}

// ===========================================================================
// GEMMs
// ===========================================================================
__global__ __launch_bounds__(256) void gemm_xw(const float* __restrict__ x,
                                               const float* __restrict__ W,
                                               const float* __restrict__ b,
                                               float* __restrict__ out) {
  __shared__ float Ws[DIM * DIM];
  for (int i = threadIdx.x; i < DIM * DIM; i += 256) Ws[i] = W[i];
  __syncthreads();
  const int c = threadIdx.x & 127;
  const int half = threadIdx.x >> 7;
  const float bias = b[c];
  for (int tile = blockIdx.x; tile < NTILES; tile += gridDim.x) {
    const int row0 = tile * 8 + half * 4;
    const float* r = x + (size_t)row0 * DIM;
    float a0 = 0.f, a1 = 0.f, a2 = 0.f, a3 = 0.f;
#pragma unroll 8
    for (int k4 = 0; k4 < 32; ++k4) {
      float4 p0 = *(const float4*)(r + 0 * DIM + k4 * 4);
      float4 p1 = *(const float4*)(r + 1 * DIM + k4 * 4);
      float4 p2 = *(const float4*)(r + 2 * DIM + k4 * 4);
      float4 p3 = *(const float4*)(r + 3 * DIM + k4 * 4);
      const float* wp = &Ws[k4 * 4 * DIM + c];
      float w0 = wp[0 * DIM], w1 = wp[1 * DIM], w2 = wp[2 * DIM], w3 = wp[3 * DIM];
      a0 += p0.x * w0 + p0.y * w1 + p0.z * w2 + p0.w * w3;
      a1 += p1.x * w0 + p1.y * w1 + p1.z * w2 + p1.w * w3;
      a2 += p2.x * w0 + p2.y * w1 + p2.z * w2 + p2.w * w3;
      a3 += p3.x * w0 + p3.y * w1 + p3.z * w2 + p3.w * w3;
    }
    out[(size_t)(row0 + 0) * DIM + c] = a0 + bias;
    out[(size_t)(row0 + 1) * DIM + c] = a1 + bias;
    out[(size_t)(row0 + 2) * DIM + c] = a2 + bias;
    out[(size_t)(row0 + 3) * DIM + c] = a3 + bias;
  }
}

// out += agg @ W_l  (agg pre-scaled by 1/deg)
__global__ __launch_bounds__(256) void gemm_aw(const float* __restrict__ agg,
                                               const float* __restrict__ W,
                                               float* __restrict__ out) {
  __shared__ float Ws[DIM * DIM];
  for (int i = threadIdx.x; i < DIM * DIM; i += 256) Ws[i] = W[i];
  __syncthreads();
  const int c = threadIdx.x & 127;
  const int half = threadIdx.x >> 7;
  for (int tile = blockIdx.x; tile < NTILES; tile += gridDim.x) {
    const int row0 = tile * 8 + half * 4;
    const float* r = agg + (size_t)row0 * DIM;
    float a0 = 0.f, a1 = 0.f, a2 = 0.f, a3 = 0.f;
#pragma unroll 8
    for (int k4 = 0; k4 < 32; ++k4) {
      float4 p0 = *(const float4*)(r + 0 * DIM + k4 * 4);
      float4 p1 = *(const float4*)(r + 1 * DIM + k4 * 4);
      float4 p2 = *(const float4*)(r + 2 * DIM + k4 * 4);
      float4 p3 = *(const float4*)(r + 3 * DIM + k4 * 4);
      const float* wp = &Ws[k4 * 4 * DIM + c];
      float w0 = wp[0 * DIM], w1 = wp[1 * DIM], w2 = wp[2 * DIM], w3 = wp[3 * DIM];
      a0 += p0.x * w0 + p0.y * w1 + p0.z * w2 + p0.w * w3;
      a1 += p1.x * w0 + p1.y * w1 + p1.z * w2 + p1.w * w3;
      a2 += p2.x * w0 + p2.y * w1 + p2.z * w2 + p2.w * w3;
      a3 += p3.x * w0 + p3.y * w1 + p3.z * w2 + p3.w * w3;
    }
    out[(size_t)(row0 + 0) * DIM + c] += a0;
    out[(size_t)(row0 + 1) * DIM + c] += a1;
    out[(size_t)(row0 + 2) * DIM + c] += a2;
    out[(size_t)(row0 + 3) * DIM + c] += a3;
  }
}

// legacy variant with per-row count scaling (fallback path)
__global__ __launch_bounds__(256) void gemm_aw_cnt(const float* __restrict__ summed,
                                                   const float* __restrict__ cnt,
                                                   const float* __restrict__ W,
                                                   float* __restrict__ out) {
  __shared__ float Ws[DIM * DIM];
  for (int i = threadIdx.x; i < DIM * DIM; i += 256) Ws[i] = W[i];
  __syncthreads();
  const int c = threadIdx.x & 127;
  const int half = threadIdx.x >> 7;
  for (int tile = blockIdx.x; tile < NTILES; tile += gridDim.x) {
    const int row0 = tile * 8 + half * 4;
    const float* r = summed + (size_t)row0 * DIM;
    float a0 = 0.f, a1 = 0.f, a2 = 0.f, a3 = 0.f;
#pragma unroll 8
    for (int k4 = 0; k4 < 32; ++k4) {
      float4 p0 = *(const float4*)(r + 0 * DIM + k4 * 4);
      float4 p1 = *(const float4*)(r + 1 * DIM + k4 * 4);
      float4 p2 = *(const float4*)(r + 2 * DIM + k4 * 4);
      float4 p3 = *(const float4*)(r + 3 * DIM + k4 * 4);
      const float* wp = &Ws[k4 * 4 * DIM + c];
      float w0 = wp[0 * DIM], w1 = wp[1 * DIM], w2 = wp[2 * DIM], w3 = wp[3 * DIM];
      a0 += p0.x * w0 + p0.y * w1 + p0.z * w2 + p0.w * w3;
      a1 += p1.x * w0 + p1.y * w1 + p1.z * w2 + p1.w * w3;
      a2 += p2.x * w0 + p2.y * w1 + p2.z * w2 + p2.w * w3;
      a3 += p3.x * w0 + p3.y * w1 + p3.z * w2 + p3.w * w3;
    }
#pragma unroll
    for (int rr = 0; rr < 4; ++rr) {
      float acc = (rr == 0) ? a0 : (rr == 1) ? a1 : (rr == 2) ? a2 : a3;
      float scale = 1.0f / fmaxf(cnt[row0 + rr], 1.0f);
      size_t idx = (size_t)(row0 + rr) * DIM + c;
      out[idx] = out[idx] + scale * acc;
    }
  }
}

extern "C" void kernel_launch(void* const* d_in, const int* in_sizes, int n_in,
                              void* d_out, int out_size, void* d_ws, size_t ws_size,
                              hipStream_t stream) {
  const float* x  = (const float*)d_in[0];
  const int*   ei = (const int*)d_in[1];
  const float* Wl = (const float*)d_in[2];
  const float* bl = (const float*)d_in[3];
  const float* Wr = (const float*)d_in[4];
  float* out = (float*)d_out;

  // CSR workspace layout (agg ends up 16B-aligned)
  int* deg      = (int*)d_ws;            // [100000]; reused as cursor after scan
  int* offsets  = deg + N_NODES;         // [100001] (reserve 100004)
  int* partials = offsets + 100004;      // [256]
  int* csr      = partials + 256;        // [NE]
  float* agg    = (float*)(csr + NE);    // [N_NODES*DIM]
  size_t needed = ((size_t)N_NODES + 100004 + 256 + NE + (size_t)N_NODES * DIM) * 4;

  if (ws_size >= needed) {
    hipMemsetAsync(deg, 0, (size_t)N_NODES * sizeof(int), stream);
    hipLaunchKernelGGL(hist_k, dim3((NE + 255) / 256), dim3(256), 0, stream, ei, deg);
    hipLaunchKernelGGL(scan_sum_k, dim3(NCHUNK), dim3(CHUNK), 0, stream, deg, partials);
    hipLaunchKernelGGL(scan_part_k, dim3(1), dim3(256), 0, stream, partials);
    // writes offsets[] and resets deg[] to serve as the fill cursor
    hipLaunchKernelGGL(scan_out_k, dim3(NCHUNK), dim3(CHUNK), 0, stream,
                       deg, partials, offsets, deg);
    hipLaunchKernelGGL(fill_k, dim3((NE + 255) / 256), dim3(256), 0, stream,
                       ei, deg, csr);
    hipLaunchKernelGGL(agg_k, dim3(N_NODES / 4), dim3(256), 0, stream,
                       offsets, csr, x, agg);
    hipLaunchKernelGGL(gemm_xw, dim3(GEMM_BLOCKS), dim3(256), 0, stream,
                       x, Wr, bl, out);
    hipLaunchKernelGGL(gemm_aw, dim3(GEMM_BLOCKS), dim3(256), 0, stream,
                       agg, Wl, out);
  } else {
    float* summed = (float*)d_ws;
    float* cnt = summed + (size_t)N_NODES * DIM;
    hipMemsetAsync(d_ws, 0, ((size_t)N_NODES * DIM + N_NODES) * sizeof(float), stream);
    hipLaunchKernelGGL(scatter_k, dim3((NE * 32) / 256), dim3(256), 0, stream,
                       ei, x, summed, cnt);
    hipLaunchKernelGGL(gemm_xw, dim3(GEMM_BLOCKS), dim3(256), 0, stream,
                       x, Wr, bl, out);
    hipLaunchKernelGGL(gemm_aw_cnt, dim3(GEMM_BLOCKS), dim3(256), 0, stream,
                       summed, cnt, Wl, out);
  }
}

// Round 4
// 401.405 us; speedup vs baseline: 8.1293x; 1.9292x over previous
//
#include <hip/hip_runtime.h>

#define N_NODES 100000
#define DIM 128
#define NE 1600000
#define NTILES (N_NODES / 8)
#define GEMM_BLOCKS 2048
#define CHUNK 512
#define NCHUNK ((N_NODES + CHUNK - 1) / CHUNK)   // 196

typedef unsigned short u16;
typedef __attribute__((ext_vector_type(8))) short bf16x8;   // 8 bf16 = 4 VGPRs
typedef __attribute__((ext_vector_type(4))) float f32x4;

__device__ __forceinline__ float bf2f(u16 h) {
  return __uint_as_float(((unsigned int)h) << 16);
}
__device__ __forceinline__ u16 f2bf(float f) {
  unsigned int u = __float_as_uint(f);
  unsigned int lsb = (u >> 16) & 1u;
  u += 0x7fffu + lsb;   // RNE
  return (u16)(u >> 16);
}

// ===========================================================================
// CSR build (shared by both paths)
// ===========================================================================
__global__ __launch_bounds__(256) void hist_k(const int* __restrict__ ei,
                                              int* __restrict__ deg) {
  int e = blockIdx.x * 256 + threadIdx.x;
  if (e < NE) atomicAdd(&deg[ei[NE + e]], 1);
}

__global__ __launch_bounds__(512) void scan_sum_k(const int* __restrict__ deg,
                                                  int* __restrict__ partials) {
  __shared__ int s[CHUNK];
  int i = blockIdx.x * CHUNK + threadIdx.x;
  s[threadIdx.x] = (i < N_NODES) ? deg[i] : 0;
  __syncthreads();
  for (int off = 256; off > 0; off >>= 1) {
    if (threadIdx.x < off) s[threadIdx.x] += s[threadIdx.x + off];
    __syncthreads();
  }
  if (threadIdx.x == 0) partials[blockIdx.x] = s[0];
}

__global__ __launch_bounds__(256) void scan_part_k(int* __restrict__ partials) {
  __shared__ int s[256];
  int t = threadIdx.x;
  int v = (t < NCHUNK) ? partials[t] : 0;
  s[t] = v;
  __syncthreads();
  for (int off = 1; off < 256; off <<= 1) {
    int add = (t >= off) ? s[t - off] : 0;
    __syncthreads();
    s[t] += add;
    __syncthreads();
  }
  if (t < NCHUNK) partials[t] = s[t] - v;   // exclusive block bases
}

__global__ __launch_bounds__(512) void scan_out_k(const int* __restrict__ deg,
                                                  const int* __restrict__ partials,
                                                  int* __restrict__ offsets,
                                                  int* __restrict__ cursor) {
  __shared__ int s[CHUNK];
  int t = threadIdx.x;
  int i = blockIdx.x * CHUNK + t;
  int v = (i < N_NODES) ? deg[i] : 0;
  s[t] = v;
  __syncthreads();
  for (int off = 1; off < CHUNK; off <<= 1) {
    int add = (t >= off) ? s[t - off] : 0;
    __syncthreads();
    s[t] += add;
    __syncthreads();
  }
  if (i < N_NODES) {
    int excl = partials[blockIdx.x] + s[t] - v;
    offsets[i] = excl;
    cursor[i] = excl;
  }
  if (i == 0) offsets[N_NODES] = NE;
}

__global__ __launch_bounds__(256) void fill_k(const int* __restrict__ ei,
                                              int* __restrict__ cursor,
                                              int* __restrict__ csr) {
  int e = blockIdx.x * 256 + threadIdx.x;
  if (e < NE) {
    int dst = ei[NE + e];
    int pos = atomicAdd(&cursor[dst], 1);
    csr[pos] = ei[e];
  }
}

// ===========================================================================
// MFMA fast path
// ===========================================================================

// x fp32 -> bf16 into cols [0,128) of packed A[N][256]
__global__ __launch_bounds__(256) void convert_k(const float* __restrict__ x,
                                                 u16* __restrict__ A) {
  int t = blockIdx.x * 256 + threadIdx.x;   // 3.2M threads, 4 elems each
  int row = t >> 5;
  int c = (t & 31) * 4;
  float4 v = *(const float4*)(x + (size_t)row * DIM + c);
  ushort4 o;
  o.x = f2bf(v.x); o.y = f2bf(v.y); o.z = f2bf(v.z); o.w = f2bf(v.w);
  *(ushort4*)(A + (size_t)row * 256 + c) = o;
}

// mean-aggregate from bf16 x (cols 0-127 of A) into cols [128,256) of A.
// One wave per node; lane covers 2 features (one dword per edge row).
__global__ __launch_bounds__(256) void agg_bf16_k(const int* __restrict__ offsets,
                                                  const int* __restrict__ csr,
                                                  u16* __restrict__ A) {
  int node = blockIdx.x * 4 + (threadIdx.x >> 6);
  int lane = threadIdx.x & 63;
  int beg = offsets[node], end = offsets[node + 1];
  float ax = 0.f, ay = 0.f;
  int i = beg;
  for (; i + 4 <= end; i += 4) {
    int s0 = csr[i], s1 = csr[i + 1], s2 = csr[i + 2], s3 = csr[i + 3];
    unsigned int u0 = *(const unsigned int*)(A + (size_t)s0 * 256 + lane * 2);
    unsigned int u1 = *(const unsigned int*)(A + (size_t)s1 * 256 + lane * 2);
    unsigned int u2 = *(const unsigned int*)(A + (size_t)s2 * 256 + lane * 2);
    unsigned int u3 = *(const unsigned int*)(A + (size_t)s3 * 256 + lane * 2);
    ax += bf2f((u16)u0) + bf2f((u16)u1) + bf2f((u16)u2) + bf2f((u16)u3);
    ay += bf2f((u16)(u0 >> 16)) + bf2f((u16)(u1 >> 16)) +
          bf2f((u16)(u2 >> 16)) + bf2f((u16)(u3 >> 16));
  }
  for (; i < end; ++i) {
    unsigned int u0 = *(const unsigned int*)(A + (size_t)csr[i] * 256 + lane * 2);
    ax += bf2f((u16)u0);
    ay += bf2f((u16)(u0 >> 16));
  }
  float scale = 1.0f / fmaxf((float)(end - beg), 1.0f);
  unsigned int p = (unsigned int)f2bf(ax * scale) |
                   ((unsigned int)f2bf(ay * scale) << 16);
  *(unsigned int*)(A + (size_t)node * 256 + 128 + lane * 2) = p;
}

// Wt[n][k] bf16: k<128 -> Wr[k][n]; k>=128 -> Wl[k-128][n]
__global__ __launch_bounds__(256) void wt_k(const float* __restrict__ Wl,
                                            const float* __restrict__ Wr,
                                            u16* __restrict__ Wt) {
  int n = blockIdx.x;       // 0..127
  int k = threadIdx.x;      // 0..255
  float v = (k < 128) ? Wr[(size_t)k * DIM + n] : Wl[(size_t)(k - 128) * DIM + n];
  Wt[(size_t)n * 256 + k] = f2bf(v);
}

// Fused GEMM: out[M=100000][128] = A[M][256](bf16) @ Wc[256][128] + b
// Block = 4 waves; wave w owns cols [w*32, w*32+32) (2 MFMA n-tiles).
// B fragments preloaded to registers once (64 VGPRs); A streamed from global
// in MFMA A-layout (lane m=lane&15, k=(lane>>4)*8+j -> one dwordx4 per kstep).
// C/D layout: col = n0 + (lane&15), row = row0 + (lane>>4)*4 + reg.
__global__ __launch_bounds__(256) void gemm_mfma(const u16* __restrict__ A,
                                                 const u16* __restrict__ Wt,
                                                 const float* __restrict__ bias,
                                                 float* __restrict__ out) {
  const int wave = threadIdx.x >> 6;
  const int lane = threadIdx.x & 63;
  const int m = lane & 15;
  const int q = lane >> 4;
  const int n0 = wave * 32;

  bf16x8 Bf[2][8];
#pragma unroll
  for (int t = 0; t < 2; ++t) {
    const u16* bp = Wt + (size_t)(n0 + t * 16 + m) * 256 + q * 8;
#pragma unroll
    for (int s = 0; s < 8; ++s) Bf[t][s] = *(const bf16x8*)(bp + s * 32);
  }
  const float b0 = bias[n0 + m];
  const float b1 = bias[n0 + 16 + m];

  for (int rt = blockIdx.x; rt < N_NODES / 16; rt += gridDim.x) {
    const int row0 = rt * 16;
    const u16* ap = A + (size_t)(row0 + m) * 256 + q * 8;
    bf16x8 Af[8];
#pragma unroll
    for (int s = 0; s < 8; ++s) Af[s] = *(const bf16x8*)(ap + s * 32);
    f32x4 acc0 = {0.f, 0.f, 0.f, 0.f};
    f32x4 acc1 = {0.f, 0.f, 0.f, 0.f};
#pragma unroll
    for (int s = 0; s < 8; ++s) {
      acc0 = __builtin_amdgcn_mfma_f32_16x16x32_bf16(Af[s], Bf[0][s], acc0, 0, 0, 0);
      acc1 = __builtin_amdgcn_mfma_f32_16x16x32_bf16(Af[s], Bf[1][s], acc1, 0, 0, 0);
    }
    float* o = out + (size_t)(row0 + q * 4) * DIM + n0 + m;
#pragma unroll
    for (int r = 0; r < 4; ++r) {
      o[(size_t)r * DIM] = acc0[r] + b0;
      o[(size_t)r * DIM + 16] = acc1[r] + b1;
    }
  }
}

// ===========================================================================
// fp32 fallback path (round-3 proven) — used only if ws too small for MFMA path
// ===========================================================================
__global__ __launch_bounds__(256) void agg_f32_k(const int* __restrict__ offsets,
                                                 const int* __restrict__ csr,
                                                 const float* __restrict__ x,
                                                 float* __restrict__ agg) {
  int node = blockIdx.x * 4 + (threadIdx.x >> 6);
  int lane = threadIdx.x & 63;
  int beg = offsets[node], end = offsets[node + 1];
  float ax = 0.f, ay = 0.f;
  int i = beg;
  for (; i + 4 <= end; i += 4) {
    int s0 = csr[i], s1 = csr[i + 1], s2 = csr[i + 2], s3 = csr[i + 3];
    float2 v0 = *(const float2*)(x + (size_t)s0 * DIM + lane * 2);
    float2 v1 = *(const float2*)(x + (size_t)s1 * DIM + lane * 2);
    float2 v2 = *(const float2*)(x + (size_t)s2 * DIM + lane * 2);
    float2 v3 = *(const float2*)(x + (size_t)s3 * DIM + lane * 2);
    ax += v0.x + v1.x + v2.x + v3.x;
    ay += v0.y + v1.y + v2.y + v3.y;
  }
  for (; i < end; ++i) {
    float2 v0 = *(const float2*)(x + (size_t)csr[i] * DIM + lane * 2);
    ax += v0.x;
    ay += v0.y;
  }
  float scale = 1.0f / fmaxf((float)(end - beg), 1.0f);
  float2 r;
  r.x = ax * scale;
  r.y = ay * scale;
  *(float2*)(agg + (size_t)node * DIM + lane * 2) = r;
}

__global__ __launch_bounds__(256) void gemm_xw(const float* __restrict__ x,
                                               const float* __restrict__ W,
                                               const float* __restrict__ b,
                                               float* __restrict__ out) {
  __shared__ float Ws[DIM * DIM];
  for (int i = threadIdx.x; i < DIM * DIM; i += 256) Ws[i] = W[i];
  __syncthreads();
  const int c = threadIdx.x & 127;
  const int half = threadIdx.x >> 7;
  const float bias = b[c];
  for (int tile = blockIdx.x; tile < NTILES; tile += gridDim.x) {
    const int row0 = tile * 8 + half * 4;
    const float* r = x + (size_t)row0 * DIM;
    float a0 = 0.f, a1 = 0.f, a2 = 0.f, a3 = 0.f;
#pragma unroll 8
    for (int k4 = 0; k4 < 32; ++k4) {
      float4 p0 = *(const float4*)(r + 0 * DIM + k4 * 4);
      float4 p1 = *(const float4*)(r + 1 * DIM + k4 * 4);
      float4 p2 = *(const float4*)(r + 2 * DIM + k4 * 4);
      float4 p3 = *(const float4*)(r + 3 * DIM + k4 * 4);
      const float* wp = &Ws[k4 * 4 * DIM + c];
      float w0 = wp[0 * DIM], w1 = wp[1 * DIM], w2 = wp[2 * DIM], w3 = wp[3 * DIM];
      a0 += p0.x * w0 + p0.y * w1 + p0.z * w2 + p0.w * w3;
      a1 += p1.x * w0 + p1.y * w1 + p1.z * w2 + p1.w * w3;
      a2 += p2.x * w0 + p2.y * w1 + p2.z * w2 + p2.w * w3;
      a3 += p3.x * w0 + p3.y * w1 + p3.z * w2 + p3.w * w3;
    }
    out[(size_t)(row0 + 0) * DIM + c] = a0 + bias;
    out[(size_t)(row0 + 1) * DIM + c] = a1 + bias;
    out[(size_t)(row0 + 2) * DIM + c] = a2 + bias;
    out[(size_t)(row0 + 3) * DIM + c] = a3 + bias;
  }
}

__global__ __launch_bounds__(256) void gemm_aw(const float* __restrict__ agg,
                                               const float* __restrict__ W,
                                               float* __restrict__ out) {
  __shared__ float Ws[DIM * DIM];
  for (int i = threadIdx.x; i < DIM * DIM; i += 256) Ws[i] = W[i];
  __syncthreads();
  const int c = threadIdx.x & 127;
  const int half = threadIdx.x >> 7;
  for (int tile = blockIdx.x; tile < NTILES; tile += gridDim.x) {
    const int row0 = tile * 8 + half * 4;
    const float* r = agg + (size_t)row0 * DIM;
    float a0 = 0.f, a1 = 0.f, a2 = 0.f, a3 = 0.f;
#pragma unroll 8
    for (int k4 = 0; k4 < 32; ++k4) {
      float4 p0 = *(const float4*)(r + 0 * DIM + k4 * 4);
      float4 p1 = *(const float4*)(r + 1 * DIM + k4 * 4);
      float4 p2 = *(const float4*)(r + 2 * DIM + k4 * 4);
      float4 p3 = *(const float4*)(r + 3 * DIM + k4 * 4);
      const float* wp = &Ws[k4 * 4 * DIM + c];
      float w0 = wp[0 * DIM], w1 = wp[1 * DIM], w2 = wp[2 * DIM], w3 = wp[3 * DIM];
      a0 += p0.x * w0 + p0.y * w1 + p0.z * w2 + p0.w * w3;
      a1 += p1.x * w0 + p1.y * w1 + p1.z * w2 + p1.w * w3;
      a2 += p2.x * w0 + p2.y * w1 + p2.z * w2 + p2.w * w3;
      a3 += p3.x * w0 + p3.y * w1 + p3.z * w2 + p3.w * w3;
    }
    out[(size_t)(row0 + 0) * DIM + c] += a0;
    out[(size_t)(row0 + 1) * DIM + c] += a1;
    out[(size_t)(row0 + 2) * DIM + c] += a2;
    out[(size_t)(row0 + 3) * DIM + c] += a3;
  }
}

extern "C" void kernel_launch(void* const* d_in, const int* in_sizes, int n_in,
                              void* d_out, int out_size, void* d_ws, size_t ws_size,
                              hipStream_t stream) {
  const float* x  = (const float*)d_in[0];
  const int*   ei = (const int*)d_in[1];
  const float* Wl = (const float*)d_in[2];
  const float* bl = (const float*)d_in[3];
  const float* Wr = (const float*)d_in[4];
  float* out = (float*)d_out;

  // --- MFMA-path workspace layout ---
  u16* A        = (u16*)d_ws;                 // [N][256] bf16 = 51.2 MB, 16B aligned
  u16* Wt       = A + (size_t)N_NODES * 256;  // [128][256] bf16 = 64 KB
  int* deg      = (int*)(Wt + 128 * 256);     // [100000]; reused as fill cursor
  int* offsets  = deg + N_NODES;              // [100001] (reserve 100004)
  int* partials = offsets + 100004;           // [256]
  int* csr      = partials + 256;             // [NE]
  size_t needed = (size_t)N_NODES * 512 + 65536 +
                  ((size_t)N_NODES + 100004 + 256 + NE) * 4;

  if (ws_size >= needed) {
    hipMemsetAsync(deg, 0, (size_t)N_NODES * sizeof(int), stream);
    hipLaunchKernelGGL(convert_k, dim3(12500), dim3(256), 0, stream, x, A);
    hipLaunchKernelGGL(hist_k, dim3((NE + 255) / 256), dim3(256), 0, stream, ei, deg);
    hipLaunchKernelGGL(scan_sum_k, dim3(NCHUNK), dim3(CHUNK), 0, stream, deg, partials);
    hipLaunchKernelGGL(scan_part_k, dim3(1), dim3(256), 0, stream, partials);
    hipLaunchKernelGGL(scan_out_k, dim3(NCHUNK), dim3(CHUNK), 0, stream,
                       deg, partials, offsets, deg);
    hipLaunchKernelGGL(fill_k, dim3((NE + 255) / 256), dim3(256), 0, stream,
                       ei, deg, csr);
    hipLaunchKernelGGL(agg_bf16_k, dim3(N_NODES / 4), dim3(256), 0, stream,
                       offsets, csr, A);
    hipLaunchKernelGGL(wt_k, dim3(128), dim3(256), 0, stream, Wl, Wr, Wt);
    hipLaunchKernelGGL(gemm_mfma, dim3(1280), dim3(256), 0, stream,
                       A, Wt, bl, out);
  } else {
    // fp32 CSR fallback (round-3 layout)
    int* deg2      = (int*)d_ws;
    int* offsets2  = deg2 + N_NODES;
    int* partials2 = offsets2 + 100004;
    int* csr2      = partials2 + 256;
    float* agg     = (float*)(csr2 + NE);
    hipMemsetAsync(deg2, 0, (size_t)N_NODES * sizeof(int), stream);
    hipLaunchKernelGGL(hist_k, dim3((NE + 255) / 256), dim3(256), 0, stream, ei, deg2);
    hipLaunchKernelGGL(scan_sum_k, dim3(NCHUNK), dim3(CHUNK), 0, stream, deg2, partials2);
    hipLaunchKernelGGL(scan_part_k, dim3(1), dim3(256), 0, stream, partials2);
    hipLaunchKernelGGL(scan_out_k, dim3(NCHUNK), dim3(CHUNK), 0, stream,
                       deg2, partials2, offsets2, deg2);
    hipLaunchKernelGGL(fill_k, dim3((NE + 255) / 256), dim3(256), 0, stream,
                       ei, deg2, csr2);
    hipLaunchKernelGGL(agg_f32_k, dim3(N_NODES / 4), dim3(256), 0, stream,
                       offsets2, csr2, x, agg);
    hipLaunchKernelGGL(gemm_xw, dim3(GEMM_BLOCKS), dim3(256), 0, stream,
                       x, Wr, bl, out);
    hipLaunchKernelGGL(gemm_aw, dim3(GEMM_BLOCKS), dim3(256), 0, stream,
                       agg, Wl, out);
  }
}

// Round 5
// 291.317 us; speedup vs baseline: 11.2012x; 1.3779x over previous
//
#include <hip/hip_runtime.h>

#define N_NODES 100000
#define DIM 128
#define NE 1600000
#define NTILES (N_NODES / 8)
#define GEMM_BLOCKS 2048
#define CHUNK 512
#define NCHUNK ((N_NODES + CHUNK - 1) / CHUNK)   // 196 (fallback path)
#define NBKT 1024                 // buckets by dst>>7; 782 actually used
#define NBUCKETS ((N_NODES + 127) / 128)          // 782
#define NBLK_BIN 200
#define EPB (NE / NBLK_BIN)       // 8000, exact
#define AGG_CAP 8192              // LDS edge cap per bucket (mean 2046, sd 45)

typedef unsigned short u16;
typedef __attribute__((ext_vector_type(8))) short bf16x8;
typedef __attribute__((ext_vector_type(4))) float f32x4;

__device__ __forceinline__ float bf2f(u16 h) {
  return __uint_as_float(((unsigned int)h) << 16);
}
__device__ __forceinline__ u16 f2bf(float f) {
  unsigned int u = __float_as_uint(f);
  unsigned int lsb = (u >> 16) & 1u;
  u += 0x7fffu + lsb;   // RNE
  return (u16)(u >> 16);
}

// ===========================================================================
// MFMA fast path
// ===========================================================================

// x fp32 -> bf16 into cols [0,128) of packed A[N][256]
__global__ __launch_bounds__(256) void convert_k(const float* __restrict__ x,
                                                 u16* __restrict__ A) {
  int t = blockIdx.x * 256 + threadIdx.x;
  int row = t >> 5;
  int c = (t & 31) * 4;
  float4 v = *(const float4*)(x + (size_t)row * DIM + c);
  ushort4 o;
  o.x = f2bf(v.x); o.y = f2bf(v.y); o.z = f2bf(v.z); o.w = f2bf(v.w);
  *(ushort4*)(A + (size_t)row * 256 + c) = o;
}

// Per-block LDS histogram of dst>>7, flushed to global bucket counts.
__global__ __launch_bounds__(256) void hist1024_k(const int* __restrict__ ei,
                                                  int* __restrict__ gh) {
  __shared__ int h[NBKT];
  for (int i = threadIdx.x; i < NBKT; i += 256) h[i] = 0;
  __syncthreads();
  int e0 = blockIdx.x * EPB;
  for (int i = threadIdx.x; i < EPB; i += 256)
    atomicAdd(&h[ei[NE + e0 + i] >> 7], 1);
  __syncthreads();
  for (int i = threadIdx.x; i < NBKT; i += 256)
    if (h[i]) atomicAdd(&gh[i], h[i]);
}

// Single-block exclusive scan of the 1024 bucket counts.
__global__ __launch_bounds__(1024) void scan1024_k(const int* __restrict__ gh,
                                                   int* __restrict__ base,
                                                   int* __restrict__ cur) {
  __shared__ int s[NBKT];
  int t = threadIdx.x;
  int v = gh[t];
  s[t] = v;
  __syncthreads();
  for (int off = 1; off < NBKT; off <<= 1) {
    int add = (t >= off) ? s[t - off] : 0;
    __syncthreads();
    s[t] += add;
    __syncthreads();
  }
  int excl = s[t] - v;
  base[t] = excl;
  cur[t] = excl;
  if (t == 0) base[NBKT] = NE;
}

// Bin edges into bucket-contiguous regions of `binned` (8B records).
// Per-(block,bucket) runs of ~10 edges -> mostly-coalesced 80B writes.
__global__ __launch_bounds__(256) void scatter_bin_k(const int* __restrict__ ei,
                                                     int* __restrict__ cur,
                                                     uint2* __restrict__ binned) {
  __shared__ int h[NBKT];
  __shared__ int bbase[NBKT];
  for (int i = threadIdx.x; i < NBKT; i += 256) h[i] = 0;
  __syncthreads();
  int e0 = blockIdx.x * EPB;
  for (int i = threadIdx.x; i < EPB; i += 256)
    atomicAdd(&h[ei[NE + e0 + i] >> 7], 1);
  __syncthreads();
  for (int i = threadIdx.x; i < NBKT; i += 256) {
    int c = h[i];
    bbase[i] = c ? atomicAdd(&cur[i], c) : 0;
    h[i] = 0;   // reuse as local cursor
  }
  __syncthreads();
  for (int i = threadIdx.x; i < EPB; i += 256) {
    int src = ei[e0 + i];
    int dst = ei[NE + e0 + i];
    int b = dst >> 7;
    int l = atomicAdd(&h[b], 1);
    binned[bbase[b] + l] = make_uint2((unsigned)src, (unsigned)dst);
  }
}

// One block per bucket (128 contiguous nodes): local counting-sort of the
// bucket's edges entirely in LDS, then wave-per-node gather-aggregate from
// bf16 x (cols 0-127 of A) into cols [128,256) of A. No global csr array.
__global__ __launch_bounds__(256) void aggB_k(const int* __restrict__ base,
                                              const uint2* __restrict__ binned,
                                              u16* __restrict__ A) {
  __shared__ int srcS[AGG_CAP];
  __shared__ int hist[128];
  __shared__ int off[128];   // inclusive scan
  __shared__ int cur[128];
  const int b = blockIdx.x;
  const int lo = base[b];
  int cnt = base[b + 1] - lo;
  if (cnt > AGG_CAP) cnt = AGG_CAP;   // impossible for this data; OOB guard

  if (threadIdx.x < 128) hist[threadIdx.x] = 0;
  __syncthreads();
  for (int i = threadIdx.x; i < cnt; i += 256)
    atomicAdd(&hist[binned[lo + i].y & 127], 1);
  __syncthreads();
  if (threadIdx.x < 128) off[threadIdx.x] = hist[threadIdx.x];
  __syncthreads();
  for (int st = 1; st < 128; st <<= 1) {
    int add = 0;
    if (threadIdx.x < 128 && threadIdx.x >= st) add = off[threadIdx.x - st];
    __syncthreads();
    if (threadIdx.x < 128) off[threadIdx.x] += add;
    __syncthreads();
  }
  if (threadIdx.x < 128) cur[threadIdx.x] = off[threadIdx.x] - hist[threadIdx.x];
  __syncthreads();
  for (int i = threadIdx.x; i < cnt; i += 256) {
    uint2 e = binned[lo + i];
    int l = atomicAdd(&cur[e.y & 127], 1);
    srcS[l] = (int)e.x;
  }
  __syncthreads();

  const int wid = threadIdx.x >> 6;
  const int lane = threadIdx.x & 63;
  const int node0 = b * 128;
  for (int ln = wid; ln < 128; ln += 4) {
    int node = node0 + ln;
    if (node >= N_NODES) break;
    int d = hist[ln];
    int e1 = off[ln];
    int j = e1 - d;
    float ax = 0.f, ay = 0.f;
    for (; j + 4 <= e1; j += 4) {
      int s0 = srcS[j], s1 = srcS[j + 1], s2 = srcS[j + 2], s3 = srcS[j + 3];
      unsigned u0 = *(const unsigned*)(A + (size_t)s0 * 256 + lane * 2);
      unsigned u1 = *(const unsigned*)(A + (size_t)s1 * 256 + lane * 2);
      unsigned u2 = *(const unsigned*)(A + (size_t)s2 * 256 + lane * 2);
      unsigned u3 = *(const unsigned*)(A + (size_t)s3 * 256 + lane * 2);
      ax += bf2f((u16)u0) + bf2f((u16)u1) + bf2f((u16)u2) + bf2f((u16)u3);
      ay += bf2f((u16)(u0 >> 16)) + bf2f((u16)(u1 >> 16)) +
            bf2f((u16)(u2 >> 16)) + bf2f((u16)(u3 >> 16));
    }
    for (; j < e1; ++j) {
      unsigned u0 = *(const unsigned*)(A + (size_t)srcS[j] * 256 + lane * 2);
      ax += bf2f((u16)u0);
      ay += bf2f((u16)(u0 >> 16));
    }
    float scale = 1.0f / fmaxf((float)d, 1.0f);
    unsigned p = (unsigned)f2bf(ax * scale) | ((unsigned)f2bf(ay * scale) << 16);
    *(unsigned*)(A + (size_t)node * 256 + 128 + lane * 2) = p;
  }
}

// Wt[n][k] bf16: k<128 -> Wr[k][n]; k>=128 -> Wl[k-128][n]
__global__ __launch_bounds__(256) void wt_k(const float* __restrict__ Wl,
                                            const float* __restrict__ Wr,
                                            u16* __restrict__ Wt) {
  int n = blockIdx.x;
  int k = threadIdx.x;
  float v = (k < 128) ? Wr[(size_t)k * DIM + n] : Wl[(size_t)(k - 128) * DIM + n];
  Wt[(size_t)n * 256 + k] = f2bf(v);
}

// Fused GEMM: out[M][128] = A[M][256](bf16) @ Wc[256][128] + b  (MFMA)
__global__ __launch_bounds__(256) void gemm_mfma(const u16* __restrict__ A,
                                                 const u16* __restrict__ Wt,
                                                 const float* __restrict__ bias,
                                                 float* __restrict__ out) {
  const int wave = threadIdx.x >> 6;
  const int lane = threadIdx.x & 63;
  const int m = lane & 15;
  const int q = lane >> 4;
  const int n0 = wave * 32;

  bf16x8 Bf[2][8];
#pragma unroll
  for (int t = 0; t < 2; ++t) {
    const u16* bp = Wt + (size_t)(n0 + t * 16 + m) * 256 + q * 8;
#pragma unroll
    for (int s = 0; s < 8; ++s) Bf[t][s] = *(const bf16x8*)(bp + s * 32);
  }
  const float b0 = bias[n0 + m];
  const float b1 = bias[n0 + 16 + m];

  for (int rt = blockIdx.x; rt < N_NODES / 16; rt += gridDim.x) {
    const int row0 = rt * 16;
    const u16* ap = A + (size_t)(row0 + m) * 256 + q * 8;
    bf16x8 Af[8];
#pragma unroll
    for (int s = 0; s < 8; ++s) Af[s] = *(const bf16x8*)(ap + s * 32);
    f32x4 acc0 = {0.f, 0.f, 0.f, 0.f};
    f32x4 acc1 = {0.f, 0.f, 0.f, 0.f};
#pragma unroll
    for (int s = 0; s < 8; ++s) {
      acc0 = __builtin_amdgcn_mfma_f32_16x16x32_bf16(Af[s], Bf[0][s], acc0, 0, 0, 0);
      acc1 = __builtin_amdgcn_mfma_f32_16x16x32_bf16(Af[s], Bf[1][s], acc1, 0, 0, 0);
    }
    float* o = out + (size_t)(row0 + q * 4) * DIM + n0 + m;
#pragma unroll
    for (int r = 0; r < 4; ++r) {
      o[(size_t)r * DIM] = acc0[r] + b0;
      o[(size_t)r * DIM + 16] = acc1[r] + b1;
    }
  }
}

// ===========================================================================
// fp32 fallback path (round-3 proven) — only if ws too small for fast path
// ===========================================================================
__global__ __launch_bounds__(256) void hist_k(const int* __restrict__ ei,
                                              int* __restrict__ deg) {
  int e = blockIdx.x * 256 + threadIdx.x;
  if (e < NE) atomicAdd(&deg[ei[NE + e]], 1);
}

__global__ __launch_bounds__(512) void scan_sum_k(const int* __restrict__ deg,
                                                  int* __restrict__ partials) {
  __shared__ int s[CHUNK];
  int i = blockIdx.x * CHUNK + threadIdx.x;
  s[threadIdx.x] = (i < N_NODES) ? deg[i] : 0;
  __syncthreads();
  for (int off = 256; off > 0; off >>= 1) {
    if (threadIdx.x < off) s[threadIdx.x] += s[threadIdx.x + off];
    __syncthreads();
  }
  if (threadIdx.x == 0) partials[blockIdx.x] = s[0];
}

__global__ __launch_bounds__(256) void scan_part_k(int* __restrict__ partials) {
  __shared__ int s[256];
  int t = threadIdx.x;
  int v = (t < NCHUNK) ? partials[t] : 0;
  s[t] = v;
  __syncthreads();
  for (int off = 1; off < 256; off <<= 1) {
    int add = (t >= off) ? s[t - off] : 0;
    __syncthreads();
    s[t] += add;
    __syncthreads();
  }
  if (t < NCHUNK) partials[t] = s[t] - v;
}

__global__ __launch_bounds__(512) void scan_out_k(const int* __restrict__ deg,
                                                  const int* __restrict__ partials,
                                                  int* __restrict__ offsets,
                                                  int* __restrict__ cursor) {
  __shared__ int s[CHUNK];
  int t = threadIdx.x;
  int i = blockIdx.x * CHUNK + t;
  int v = (i < N_NODES) ? deg[i] : 0;
  s[t] = v;
  __syncthreads();
  for (int off = 1; off < CHUNK; off <<= 1) {
    int add = (t >= off) ? s[t - off] : 0;
    __syncthreads();
    s[t] += add;
    __syncthreads();
  }
  if (i < N_NODES) {
    int excl = partials[blockIdx.x] + s[t] - v;
    offsets[i] = excl;
    cursor[i] = excl;
  }
  if (i == 0) offsets[N_NODES] = NE;
}

__global__ __launch_bounds__(256) void fill_k(const int* __restrict__ ei,
                                              int* __restrict__ cursor,
                                              int* __restrict__ csr) {
  int e = blockIdx.x * 256 + threadIdx.x;
  if (e < NE) {
    int dst = ei[NE + e];
    int pos = atomicAdd(&cursor[dst], 1);
    csr[pos] = ei[e];
  }
}

__global__ __launch_bounds__(256) void agg_f32_k(const int* __restrict__ offsets,
                                                 const int* __restrict__ csr,
                                                 const float* __restrict__ x,
                                                 float* __restrict__ agg) {
  int node = blockIdx.x * 4 + (threadIdx.x >> 6);
  int lane = threadIdx.x & 63;
  int beg = offsets[node], end = offsets[node + 1];
  float ax = 0.f, ay = 0.f;
  int i = beg;
  for (; i + 4 <= end; i += 4) {
    int s0 = csr[i], s1 = csr[i + 1], s2 = csr[i + 2], s3 = csr[i + 3];
    float2 v0 = *(const float2*)(x + (size_t)s0 * DIM + lane * 2);
    float2 v1 = *(const float2*)(x + (size_t)s1 * DIM + lane * 2);
    float2 v2 = *(const float2*)(x + (size_t)s2 * DIM + lane * 2);
    float2 v3 = *(const float2*)(x + (size_t)s3 * DIM + lane * 2);
    ax += v0.x + v1.x + v2.x + v3.x;
    ay += v0.y + v1.y + v2.y + v3.y;
  }
  for (; i < end; ++i) {
    float2 v0 = *(const float2*)(x + (size_t)csr[i] * DIM + lane * 2);
    ax += v0.x;
    ay += v0.y;
  }
  float scale = 1.0f / fmaxf((float)(end - beg), 1.0f);
  float2 r;
  r.x = ax * scale;
  r.y = ay * scale;
  *(float2*)(agg + (size_t)node * DIM + lane * 2) = r;
}

__global__ __launch_bounds__(256) void gemm_xw(const float* __restrict__ x,
                                               const float* __restrict__ W,
                                               const float* __restrict__ b,
                                               float* __restrict__ out) {
  __shared__ float Ws[DIM * DIM];
  for (int i = threadIdx.x; i < DIM * DIM; i += 256) Ws[i] = W[i];
  __syncthreads();
  const int c = threadIdx.x & 127;
  const int half = threadIdx.x >> 7;
  const float bias = b[c];
  for (int tile = blockIdx.x; tile < NTILES; tile += gridDim.x) {
    const int row0 = tile * 8 + half * 4;
    const float* r = x + (size_t)row0 * DIM;
    float a0 = 0.f, a1 = 0.f, a2 = 0.f, a3 = 0.f;
#pragma unroll 8
    for (int k4 = 0; k4 < 32; ++k4) {
      float4 p0 = *(const float4*)(r + 0 * DIM + k4 * 4);
      float4 p1 = *(const float4*)(r + 1 * DIM + k4 * 4);
      float4 p2 = *(const float4*)(r + 2 * DIM + k4 * 4);
      float4 p3 = *(const float4*)(r + 3 * DIM + k4 * 4);
      const float* wp = &Ws[k4 * 4 * DIM + c];
      float w0 = wp[0 * DIM], w1 = wp[1 * DIM], w2 = wp[2 * DIM], w3 = wp[3 * DIM];
      a0 += p0.x * w0 + p0.y * w1 + p0.z * w2 + p0.w * w3;
      a1 += p1.x * w0 + p1.y * w1 + p1.z * w2 + p1.w * w3;
      a2 += p2.x * w0 + p2.y * w1 + p2.z * w2 + p2.w * w3;
      a3 += p3.x * w0 + p3.y * w1 + p3.z * w2 + p3.w * w3;
    }
    out[(size_t)(row0 + 0) * DIM + c] = a0 + bias;
    out[(size_t)(row0 + 1) * DIM + c] = a1 + bias;
    out[(size_t)(row0 + 2) * DIM + c] = a2 + bias;
    out[(size_t)(row0 + 3) * DIM + c] = a3 + bias;
  }
}

__global__ __launch_bounds__(256) void gemm_aw(const float* __restrict__ agg,
                                               const float* __restrict__ W,
                                               float* __restrict__ out) {
  __shared__ float Ws[DIM * DIM];
  for (int i = threadIdx.x; i < DIM * DIM; i += 256) Ws[i] = W[i];
  __syncthreads();
  const int c = threadIdx.x & 127;
  const int half = threadIdx.x >> 7;
  for (int tile = blockIdx.x; tile < NTILES; tile += gridDim.x) {
    const int row0 = tile * 8 + half * 4;
    const float* r = agg + (size_t)row0 * DIM;
    float a0 = 0.f, a1 = 0.f, a2 = 0.f, a3 = 0.f;
#pragma unroll 8
    for (int k4 = 0; k4 < 32; ++k4) {
      float4 p0 = *(const float4*)(r + 0 * DIM + k4 * 4);
      float4 p1 = *(const float4*)(r + 1 * DIM + k4 * 4);
      float4 p2 = *(const float4*)(r + 2 * DIM + k4 * 4);
      float4 p3 = *(const float4*)(r + 3 * DIM + k4 * 4);
      const float* wp = &Ws[k4 * 4 * DIM + c];
      float w0 = wp[0 * DIM], w1 = wp[1 * DIM], w2 = wp[2 * DIM], w3 = wp[3 * DIM];
      a0 += p0.x * w0 + p0.y * w1 + p0.z * w2 + p0.w * w3;
      a1 += p1.x * w0 + p1.y * w1 + p1.z * w2 + p1.w * w3;
      a2 += p2.x * w0 + p2.y * w1 + p2.z * w2 + p2.w * w3;
      a3 += p3.x * w0 + p3.y * w1 + p3.z * w2 + p3.w * w3;
    }
    out[(size_t)(row0 + 0) * DIM + c] += a0;
    out[(size_t)(row0 + 1) * DIM + c] += a1;
    out[(size_t)(row0 + 2) * DIM + c] += a2;
    out[(size_t)(row0 + 3) * DIM + c] += a3;
  }
}

extern "C" void kernel_launch(void* const* d_in, const int* in_sizes, int n_in,
                              void* d_out, int out_size, void* d_ws, size_t ws_size,
                              hipStream_t stream) {
  const float* x  = (const float*)d_in[0];
  const int*   ei = (const int*)d_in[1];
  const float* Wl = (const float*)d_in[2];
  const float* bl = (const float*)d_in[3];
  const float* Wr = (const float*)d_in[4];
  float* out = (float*)d_out;

  // --- fast-path workspace layout ---
  u16* A         = (u16*)d_ws;                  // [N][256] bf16 = 51.2 MB
  u16* Wt        = A + (size_t)N_NODES * 256;   // [128][256] bf16 = 64 KB
  uint2* binned  = (uint2*)(Wt + 128 * 256);    // [NE] 8B = 12.8 MB
  int* bktHist   = (int*)(binned + NE);         // [1024]
  int* bktBase   = bktHist + NBKT;              // [1025]
  int* bktCur    = bktBase + NBKT + 1;          // [1024]
  size_t needed  = (size_t)N_NODES * 512 + 65536 + (size_t)NE * 8 +
                   (NBKT + NBKT + 1 + NBKT) * 4;

  if (ws_size >= needed) {
    hipMemsetAsync(bktHist, 0, NBKT * sizeof(int), stream);
    hipLaunchKernelGGL(convert_k, dim3(12500), dim3(256), 0, stream, x, A);
    hipLaunchKernelGGL(hist1024_k, dim3(NBLK_BIN), dim3(256), 0, stream, ei, bktHist);
    hipLaunchKernelGGL(scan1024_k, dim3(1), dim3(1024), 0, stream,
                       bktHist, bktBase, bktCur);
    hipLaunchKernelGGL(scatter_bin_k, dim3(NBLK_BIN), dim3(256), 0, stream,
                       ei, bktCur, binned);
    hipLaunchKernelGGL(aggB_k, dim3(NBUCKETS), dim3(256), 0, stream,
                       bktBase, binned, A);
    hipLaunchKernelGGL(wt_k, dim3(128), dim3(256), 0, stream, Wl, Wr, Wt);
    hipLaunchKernelGGL(gemm_mfma, dim3(1280), dim3(256), 0, stream,
                       A, Wt, bl, out);
  } else {
    // fp32 CSR fallback (round-3 layout)
    int* deg2      = (int*)d_ws;
    int* offsets2  = deg2 + N_NODES;
    int* partials2 = offsets2 + 100004;
    int* csr2      = partials2 + 256;
    float* agg     = (float*)(csr2 + NE);
    hipMemsetAsync(deg2, 0, (size_t)N_NODES * sizeof(int), stream);
    hipLaunchKernelGGL(hist_k, dim3((NE + 255) / 256), dim3(256), 0, stream, ei, deg2);
    hipLaunchKernelGGL(scan_sum_k, dim3(NCHUNK), dim3(CHUNK), 0, stream, deg2, partials2);
    hipLaunchKernelGGL(scan_part_k, dim3(1), dim3(256), 0, stream, partials2);
    hipLaunchKernelGGL(scan_out_k, dim3(NCHUNK), dim3(CHUNK), 0, stream,
                       deg2, partials2, offsets2, deg2);
    hipLaunchKernelGGL(fill_k, dim3((NE + 255) / 256), dim3(256), 0, stream,
                       ei, deg2, csr2);
    hipLaunchKernelGGL(agg_f32_k, dim3(N_NODES / 4), dim3(256), 0, stream,
                       offsets2, csr2, x, agg);
    hipLaunchKernelGGL(gemm_xw, dim3(GEMM_BLOCKS), dim3(256), 0, stream,
                       x, Wr, bl, out);
    hipLaunchKernelGGL(gemm_aw, dim3(GEMM_BLOCKS), dim3(256), 0, stream,
                       agg, Wl, out);
  }
}

// Round 6
// 270.785 us; speedup vs baseline: 12.0506x; 1.0758x over previous
//
#include <hip/hip_runtime.h>

#define N_NODES 100000
#define DIM 128
#define NE 1600000
#define NTILES (N_NODES / 8)
#define GEMM_BLOCKS 2048
#define CHUNK 512
#define NCHUNK ((N_NODES + CHUNK - 1) / CHUNK)   // fallback path
#define NBKT2 2048                // buckets by dst>>6; 1563 actually used
#define NB64 ((N_NODES + 63) / 64)               // 1563
#define NBLK_BIN 200
#define EPB (NE / NBLK_BIN)       // 8000, exact
#define BK_CAP 2048               // LDS edge cap per 64-node bucket (mean 1024, sd 32)

typedef unsigned short u16;
typedef __attribute__((ext_vector_type(8))) short bf16x8;
typedef __attribute__((ext_vector_type(4))) float f32x4;

__device__ __forceinline__ float bf2f(u16 h) {
  return __uint_as_float(((unsigned int)h) << 16);
}
__device__ __forceinline__ u16 f2bf(float f) {
  unsigned int u = __float_as_uint(f);
  unsigned int lsb = (u >> 16) & 1u;
  u += 0x7fffu + lsb;   // RNE
  return (u16)(u >> 16);
}

// ===========================================================================
// MFMA fast path
// ===========================================================================

// x fp32 -> bf16 into cols [0,128) of packed A[N][256]
__global__ __launch_bounds__(256) void convert_k(const float* __restrict__ x,
                                                 u16* __restrict__ A) {
  int t = blockIdx.x * 256 + threadIdx.x;
  int row = t >> 5;
  int c = (t & 31) * 4;
  float4 v = *(const float4*)(x + (size_t)row * DIM + c);
  ushort4 o;
  o.x = f2bf(v.x); o.y = f2bf(v.y); o.z = f2bf(v.z); o.w = f2bf(v.w);
  *(ushort4*)(A + (size_t)row * 256 + c) = o;
}

// Per-block LDS histogram of dst>>6, flushed to global bucket counts.
__global__ __launch_bounds__(256) void hist2048_k(const int* __restrict__ ei,
                                                  int* __restrict__ gh) {
  __shared__ int h[NBKT2];
  for (int i = threadIdx.x; i < NBKT2; i += 256) h[i] = 0;
  __syncthreads();
  int e0 = blockIdx.x * EPB;
  for (int i = threadIdx.x; i < EPB; i += 256)
    atomicAdd(&h[ei[NE + e0 + i] >> 6], 1);
  __syncthreads();
  for (int i = threadIdx.x; i < NBKT2; i += 256)
    if (h[i]) atomicAdd(&gh[i], h[i]);
}

// Single-block exclusive scan of 2048 bucket counts (pair per thread).
__global__ __launch_bounds__(1024) void scan2048_k(const int* __restrict__ gh,
                                                   int* __restrict__ base,
                                                   int* __restrict__ cur) {
  __shared__ int p[1024];
  int t = threadIdx.x;
  int a = gh[2 * t], b = gh[2 * t + 1];
  p[t] = a + b;
  __syncthreads();
  for (int off = 1; off < 1024; off <<= 1) {
    int add = (t >= off) ? p[t - off] : 0;
    __syncthreads();
    p[t] += add;
    __syncthreads();
  }
  int e0 = p[t] - (a + b);   // exclusive prefix at index 2t
  base[2 * t] = e0;       cur[2 * t] = e0;
  base[2 * t + 1] = e0 + a; cur[2 * t + 1] = e0 + a;
  if (t == 1023) base[NBKT2] = p[t];   // = NE
}

// Bin edges into bucket-contiguous regions as packed 4B records:
// rec = (dst&63)<<17 | src   (src < 2^17)
__global__ __launch_bounds__(256) void scatter_bin_k(const int* __restrict__ ei,
                                                     int* __restrict__ cur,
                                                     int* __restrict__ binned) {
  __shared__ int h[NBKT2];
  __shared__ int bbase[NBKT2];
  for (int i = threadIdx.x; i < NBKT2; i += 256) h[i] = 0;
  __syncthreads();
  int e0 = blockIdx.x * EPB;
  for (int i = threadIdx.x; i < EPB; i += 256)
    atomicAdd(&h[ei[NE + e0 + i] >> 6], 1);
  __syncthreads();
  for (int i = threadIdx.x; i < NBKT2; i += 256) {
    int c = h[i];
    bbase[i] = c ? atomicAdd(&cur[i], c) : 0;
    h[i] = 0;   // reuse as local cursor
  }
  __syncthreads();
  for (int i = threadIdx.x; i < EPB; i += 256) {
    int src = ei[e0 + i];
    int dst = ei[NE + e0 + i];
    int b = dst >> 6;
    int l = atomicAdd(&h[b], 1);
    binned[bbase[b] + l] = ((dst & 63) << 17) | src;
  }
}

// One block per 64-node bucket: LDS counting-sort of ~1024 packed records,
// then wave-per-node gather-aggregate from bf16 x (cols 0-127 of A) into
// cols [128,256) of A. LDS ~9KB -> high occupancy; grid 1563 blocks.
__global__ __launch_bounds__(256) void aggB_k(const int* __restrict__ base,
                                              const int* __restrict__ binned,
                                              u16* __restrict__ A) {
  __shared__ int srcS[BK_CAP];
  __shared__ int hist[64];
  __shared__ int off[64];   // inclusive scan
  __shared__ int cur[64];
  const int b = blockIdx.x;
  const int lo = base[b];
  int cnt = base[b + 1] - lo;
  if (cnt > BK_CAP) cnt = BK_CAP;   // statistical impossibility; OOB guard

  if (threadIdx.x < 64) hist[threadIdx.x] = 0;
  __syncthreads();
  for (int i = threadIdx.x; i < cnt; i += 256)
    atomicAdd(&hist[binned[lo + i] >> 17], 1);
  __syncthreads();
  if (threadIdx.x < 64) off[threadIdx.x] = hist[threadIdx.x];
  __syncthreads();
  for (int st = 1; st < 64; st <<= 1) {
    int add = 0;
    if (threadIdx.x < 64 && threadIdx.x >= st) add = off[threadIdx.x - st];
    __syncthreads();
    if (threadIdx.x < 64) off[threadIdx.x] += add;
    __syncthreads();
  }
  if (threadIdx.x < 64) cur[threadIdx.x] = off[threadIdx.x] - hist[threadIdx.x];
  __syncthreads();
  for (int i = threadIdx.x; i < cnt; i += 256) {
    int rec = binned[lo + i];
    int l = atomicAdd(&cur[rec >> 17], 1);
    srcS[l] = rec & 0x1FFFF;
  }
  __syncthreads();

  const int wid = threadIdx.x >> 6;
  const int lane = threadIdx.x & 63;
  const int node0 = b * 64;
  for (int ln = wid; ln < 64; ln += 4) {
    int node = node0 + ln;
    if (node >= N_NODES) break;
    int d = hist[ln];
    int e1 = off[ln];
    int j = e1 - d;
    float ax = 0.f, ay = 0.f;
    for (; j + 4 <= e1; j += 4) {
      int s0 = srcS[j], s1 = srcS[j + 1], s2 = srcS[j + 2], s3 = srcS[j + 3];
      unsigned u0 = *(const unsigned*)(A + (size_t)s0 * 256 + lane * 2);
      unsigned u1 = *(const unsigned*)(A + (size_t)s1 * 256 + lane * 2);
      unsigned u2 = *(const unsigned*)(A + (size_t)s2 * 256 + lane * 2);
      unsigned u3 = *(const unsigned*)(A + (size_t)s3 * 256 + lane * 2);
      ax += bf2f((u16)u0) + bf2f((u16)u1) + bf2f((u16)u2) + bf2f((u16)u3);
      ay += bf2f((u16)(u0 >> 16)) + bf2f((u16)(u1 >> 16)) +
            bf2f((u16)(u2 >> 16)) + bf2f((u16)(u3 >> 16));
    }
    for (; j < e1; ++j) {
      unsigned u0 = *(const unsigned*)(A + (size_t)srcS[j] * 256 + lane * 2);
      ax += bf2f((u16)u0);
      ay += bf2f((u16)(u0 >> 16));
    }
    float scale = 1.0f / fmaxf((float)d, 1.0f);
    unsigned p = (unsigned)f2bf(ax * scale) | ((unsigned)f2bf(ay * scale) << 16);
    *(unsigned*)(A + (size_t)node * 256 + 128 + lane * 2) = p;
  }
}

// Wt[n][k] bf16: k<128 -> Wr[k][n]; k>=128 -> Wl[k-128][n]
__global__ __launch_bounds__(256) void wt_k(const float* __restrict__ Wl,
                                            const float* __restrict__ Wr,
                                            u16* __restrict__ Wt) {
  int n = blockIdx.x;
  int k = threadIdx.x;
  float v = (k < 128) ? Wr[(size_t)k * DIM + n] : Wl[(size_t)(k - 128) * DIM + n];
  Wt[(size_t)n * 256 + k] = f2bf(v);
}

// Fused GEMM: out[M][128] = A[M][256](bf16) @ Wc[256][128] + b  (MFMA)
__global__ __launch_bounds__(256) void gemm_mfma(const u16* __restrict__ A,
                                                 const u16* __restrict__ Wt,
                                                 const float* __restrict__ bias,
                                                 float* __restrict__ out) {
  const int wave = threadIdx.x >> 6;
  const int lane = threadIdx.x & 63;
  const int m = lane & 15;
  const int q = lane >> 4;
  const int n0 = wave * 32;

  bf16x8 Bf[2][8];
#pragma unroll
  for (int t = 0; t < 2; ++t) {
    const u16* bp = Wt + (size_t)(n0 + t * 16 + m) * 256 + q * 8;
#pragma unroll
    for (int s = 0; s < 8; ++s) Bf[t][s] = *(const bf16x8*)(bp + s * 32);
  }
  const float b0 = bias[n0 + m];
  const float b1 = bias[n0 + 16 + m];

  for (int rt = blockIdx.x; rt < N_NODES / 16; rt += gridDim.x) {
    const int row0 = rt * 16;
    const u16* ap = A + (size_t)(row0 + m) * 256 + q * 8;
    bf16x8 Af[8];
#pragma unroll
    for (int s = 0; s < 8; ++s) Af[s] = *(const bf16x8*)(ap + s * 32);
    f32x4 acc0 = {0.f, 0.f, 0.f, 0.f};
    f32x4 acc1 = {0.f, 0.f, 0.f, 0.f};
#pragma unroll
    for (int s = 0; s < 8; ++s) {
      acc0 = __builtin_amdgcn_mfma_f32_16x16x32_bf16(Af[s], Bf[0][s], acc0, 0, 0, 0);
      acc1 = __builtin_amdgcn_mfma_f32_16x16x32_bf16(Af[s], Bf[1][s], acc1, 0, 0, 0);
    }
    float* o = out + (size_t)(row0 + q * 4) * DIM + n0 + m;
#pragma unroll
    for (int r = 0; r < 4; ++r) {
      o[(size_t)r * DIM] = acc0[r] + b0;
      o[(size_t)r * DIM + 16] = acc1[r] + b1;
    }
  }
}

// ===========================================================================
// fp32 fallback path (round-3 proven) — only if ws too small for fast path
// ===========================================================================
__global__ __launch_bounds__(256) void hist_k(const int* __restrict__ ei,
                                              int* __restrict__ deg) {
  int e = blockIdx.x * 256 + threadIdx.x;
  if (e < NE) atomicAdd(&deg[ei[NE + e]], 1);
}

__global__ __launch_bounds__(512) void scan_sum_k(const int* __restrict__ deg,
                                                  int* __restrict__ partials) {
  __shared__ int s[CHUNK];
  int i = blockIdx.x * CHUNK + threadIdx.x;
  s[threadIdx.x] = (i < N_NODES) ? deg[i] : 0;
  __syncthreads();
  for (int off = 256; off > 0; off >>= 1) {
    if (threadIdx.x < off) s[threadIdx.x] += s[threadIdx.x + off];
    __syncthreads();
  }
  if (threadIdx.x == 0) partials[blockIdx.x] = s[0];
}

__global__ __launch_bounds__(256) void scan_part_k(int* __restrict__ partials) {
  __shared__ int s[256];
  int t = threadIdx.x;
  int v = (t < NCHUNK) ? partials[t] : 0;
  s[t] = v;
  __syncthreads();
  for (int off = 1; off < 256; off <<= 1) {
    int add = (t >= off) ? s[t - off] : 0;
    __syncthreads();
    s[t] += add;
    __syncthreads();
  }
  if (t < NCHUNK) partials[t] = s[t] - v;
}

__global__ __launch_bounds__(512) void scan_out_k(const int* __restrict__ deg,
                                                  const int* __restrict__ partials,
                                                  int* __restrict__ offsets,
                                                  int* __restrict__ cursor) {
  __shared__ int s[CHUNK];
  int t = threadIdx.x;
  int i = blockIdx.x * CHUNK + t;
  int v = (i < N_NODES) ? deg[i] : 0;
  s[t] = v;
  __syncthreads();
  for (int off = 1; off < CHUNK; off <<= 1) {
    int add = (t >= off) ? s[t - off] : 0;
    __syncthreads();
    s[t] += add;
    __syncthreads();
  }
  if (i < N_NODES) {
    int excl = partials[blockIdx.x] + s[t] - v;
    offsets[i] = excl;
    cursor[i] = excl;
  }
  if (i == 0) offsets[N_NODES] = NE;
}

__global__ __launch_bounds__(256) void fill_k(const int* __restrict__ ei,
                                              int* __restrict__ cursor,
                                              int* __restrict__ csr) {
  int e = blockIdx.x * 256 + threadIdx.x;
  if (e < NE) {
    int dst = ei[NE + e];
    int pos = atomicAdd(&cursor[dst], 1);
    csr[pos] = ei[e];
  }
}

__global__ __launch_bounds__(256) void agg_f32_k(const int* __restrict__ offsets,
                                                 const int* __restrict__ csr,
                                                 const float* __restrict__ x,
                                                 float* __restrict__ agg) {
  int node = blockIdx.x * 4 + (threadIdx.x >> 6);
  int lane = threadIdx.x & 63;
  int beg = offsets[node], end = offsets[node + 1];
  float ax = 0.f, ay = 0.f;
  int i = beg;
  for (; i + 4 <= end; i += 4) {
    int s0 = csr[i], s1 = csr[i + 1], s2 = csr[i + 2], s3 = csr[i + 3];
    float2 v0 = *(const float2*)(x + (size_t)s0 * DIM + lane * 2);
    float2 v1 = *(const float2*)(x + (size_t)s1 * DIM + lane * 2);
    float2 v2 = *(const float2*)(x + (size_t)s2 * DIM + lane * 2);
    float2 v3 = *(const float2*)(x + (size_t)s3 * DIM + lane * 2);
    ax += v0.x + v1.x + v2.x + v3.x;
    ay += v0.y + v1.y + v2.y + v3.y;
  }
  for (; i < end; ++i) {
    float2 v0 = *(const float2*)(x + (size_t)csr[i] * DIM + lane * 2);
    ax += v0.x;
    ay += v0.y;
  }
  float scale = 1.0f / fmaxf((float)(end - beg), 1.0f);
  float2 r;
  r.x = ax * scale;
  r.y = ay * scale;
  *(float2*)(agg + (size_t)node * DIM + lane * 2) = r;
}

__global__ __launch_bounds__(256) void gemm_xw(const float* __restrict__ x,
                                               const float* __restrict__ W,
                                               const float* __restrict__ b,
                                               float* __restrict__ out) {
  __shared__ float Ws[DIM * DIM];
  for (int i = threadIdx.x; i < DIM * DIM; i += 256) Ws[i] = W[i];
  __syncthreads();
  const int c = threadIdx.x & 127;
  const int half = threadIdx.x >> 7;
  const float bias = b[c];
  for (int tile = blockIdx.x; tile < NTILES; tile += gridDim.x) {
    const int row0 = tile * 8 + half * 4;
    const float* r = x + (size_t)row0 * DIM;
    float a0 = 0.f, a1 = 0.f, a2 = 0.f, a3 = 0.f;
#pragma unroll 8
    for (int k4 = 0; k4 < 32; ++k4) {
      float4 p0 = *(const float4*)(r + 0 * DIM + k4 * 4);
      float4 p1 = *(const float4*)(r + 1 * DIM + k4 * 4);
      float4 p2 = *(const float4*)(r + 2 * DIM + k4 * 4);
      float4 p3 = *(const float4*)(r + 3 * DIM + k4 * 4);
      const float* wp = &Ws[k4 * 4 * DIM + c];
      float w0 = wp[0 * DIM], w1 = wp[1 * DIM], w2 = wp[2 * DIM], w3 = wp[3 * DIM];
      a0 += p0.x * w0 + p0.y * w1 + p0.z * w2 + p0.w * w3;
      a1 += p1.x * w0 + p1.y * w1 + p1.z * w2 + p1.w * w3;
      a2 += p2.x * w0 + p2.y * w1 + p2.z * w2 + p2.w * w3;
      a3 += p3.x * w0 + p3.y * w1 + p3.z * w2 + p3.w * w3;
    }
    out[(size_t)(row0 + 0) * DIM + c] = a0 + bias;
    out[(size_t)(row0 + 1) * DIM + c] = a1 + bias;
    out[(size_t)(row0 + 2) * DIM + c] = a2 + bias;
    out[(size_t)(row0 + 3) * DIM + c] = a3 + bias;
  }
}

__global__ __launch_bounds__(256) void gemm_aw(const float* __restrict__ agg,
                                               const float* __restrict__ W,
                                               float* __restrict__ out) {
  __shared__ float Ws[DIM * DIM];
  for (int i = threadIdx.x; i < DIM * DIM; i += 256) Ws[i] = W[i];
  __syncthreads();
  const int c = threadIdx.x & 127;
  const int half = threadIdx.x >> 7;
  for (int tile = blockIdx.x; tile < NTILES; tile += gridDim.x) {
    const int row0 = tile * 8 + half * 4;
    const float* r = agg + (size_t)row0 * DIM;
    float a0 = 0.f, a1 = 0.f, a2 = 0.f, a3 = 0.f;
#pragma unroll 8
    for (int k4 = 0; k4 < 32; ++k4) {
      float4 p0 = *(const float4*)(r + 0 * DIM + k4 * 4);
      float4 p1 = *(const float4*)(r + 1 * DIM + k4 * 4);
      float4 p2 = *(const float4*)(r + 2 * DIM + k4 * 4);
      float4 p3 = *(const float4*)(r + 3 * DIM + k4 * 4);
      const float* wp = &Ws[k4 * 4 * DIM + c];
      float w0 = wp[0 * DIM], w1 = wp[1 * DIM], w2 = wp[2 * DIM], w3 = wp[3 * DIM];
      a0 += p0.x * w0 + p0.y * w1 + p0.z * w2 + p0.w * w3;
      a1 += p1.x * w0 + p1.y * w1 + p1.z * w2 + p1.w * w3;
      a2 += p2.x * w0 + p2.y * w1 + p2.z * w2 + p2.w * w3;
      a3 += p3.x * w0 + p3.y * w1 + p3.z * w2 + p3.w * w3;
    }
    out[(size_t)(row0 + 0) * DIM + c] += a0;
    out[(size_t)(row0 + 1) * DIM + c] += a1;
    out[(size_t)(row0 + 2) * DIM + c] += a2;
    out[(size_t)(row0 + 3) * DIM + c] += a3;
  }
}

extern "C" void kernel_launch(void* const* d_in, const int* in_sizes, int n_in,
                              void* d_out, int out_size, void* d_ws, size_t ws_size,
                              hipStream_t stream) {
  const float* x  = (const float*)d_in[0];
  const int*   ei = (const int*)d_in[1];
  const float* Wl = (const float*)d_in[2];
  const float* bl = (const float*)d_in[3];
  const float* Wr = (const float*)d_in[4];
  float* out = (float*)d_out;

  // --- fast-path workspace layout ---
  u16* A        = (u16*)d_ws;                  // [N][256] bf16 = 51.2 MB
  u16* Wt       = A + (size_t)N_NODES * 256;   // [128][256] bf16 = 64 KB
  int* binned   = (int*)(Wt + 128 * 256);      // [NE] 4B packed = 6.4 MB
  int* bktHist  = binned + NE;                 // [2048]
  int* bktBase  = bktHist + NBKT2;             // [2049]
  int* bktCur   = bktBase + NBKT2 + 1;         // [2048]
  size_t needed = (size_t)N_NODES * 512 + 65536 + (size_t)NE * 4 +
                  (NBKT2 + NBKT2 + 1 + NBKT2) * 4;

  if (ws_size >= needed) {
    hipMemsetAsync(bktHist, 0, NBKT2 * sizeof(int), stream);
    hipLaunchKernelGGL(convert_k, dim3(12500), dim3(256), 0, stream, x, A);
    hipLaunchKernelGGL(hist2048_k, dim3(NBLK_BIN), dim3(256), 0, stream, ei, bktHist);
    hipLaunchKernelGGL(scan2048_k, dim3(1), dim3(1024), 0, stream,
                       bktHist, bktBase, bktCur);
    hipLaunchKernelGGL(scatter_bin_k, dim3(NBLK_BIN), dim3(256), 0, stream,
                       ei, bktCur, binned);
    hipLaunchKernelGGL(aggB_k, dim3(NB64), dim3(256), 0, stream,
                       bktBase, binned, A);
    hipLaunchKernelGGL(wt_k, dim3(128), dim3(256), 0, stream, Wl, Wr, Wt);
    hipLaunchKernelGGL(gemm_mfma, dim3(1280), dim3(256), 0, stream,
                       A, Wt, bl, out);
  } else {
    // fp32 CSR fallback (round-3 layout)
    int* deg2      = (int*)d_ws;
    int* offsets2  = deg2 + N_NODES;
    int* partials2 = offsets2 + 100004;
    int* csr2      = partials2 + 256;
    float* agg     = (float*)(csr2 + NE);
    hipMemsetAsync(deg2, 0, (size_t)N_NODES * sizeof(int), stream);
    hipLaunchKernelGGL(hist_k, dim3((NE + 255) / 256), dim3(256), 0, stream, ei, deg2);
    hipLaunchKernelGGL(scan_sum_k, dim3(NCHUNK), dim3(CHUNK), 0, stream, deg2, partials2);
    hipLaunchKernelGGL(scan_part_k, dim3(1), dim3(256), 0, stream, partials2);
    hipLaunchKernelGGL(scan_out_k, dim3(NCHUNK), dim3(CHUNK), 0, stream,
                       deg2, partials2, offsets2, deg2);
    hipLaunchKernelGGL(fill_k, dim3((NE + 255) / 256), dim3(256), 0, stream,
                       ei, deg2, csr2);
    hipLaunchKernelGGL(agg_f32_k, dim3(N_NODES / 4), dim3(256), 0, stream,
                       offsets2, csr2, x, agg);
    hipLaunchKernelGGL(gemm_xw, dim3(GEMM_BLOCKS), dim3(256), 0, stream,
                       x, Wr, bl, out);
    hipLaunchKernelGGL(gemm_aw, dim3(GEMM_BLOCKS), dim3(256), 0, stream,
                       agg, Wl, out);
  }
}

// Round 7
// 265.999 us; speedup vs baseline: 12.2674x; 1.0180x over previous
//
#include <hip/hip_runtime.h>

#define N_NODES 100000
#define DIM 128
#define NE 1600000
#define NTILES (N_NODES / 8)
#define GEMM_BLOCKS 2048
#define CHUNK 512
#define NCHUNK ((N_NODES + CHUNK - 1) / CHUNK)   // fallback path
#define NBKT 4096                 // buckets by dst>>5; 3125 actually used
#define NB32 (N_NODES / 32)       // 3125, exact
#define NBLK_BIN 200
#define EPB (NE / NBLK_BIN)       // 8000, exact
#define BK_CAP 1024               // per-32-node-bucket edge cap (mean 512, sd 23)

typedef unsigned short u16;
typedef __attribute__((ext_vector_type(8))) short bf16x8;
typedef __attribute__((ext_vector_type(4))) float f32x4;

__device__ __forceinline__ float bf2f(u16 h) {
  return __uint_as_float(((unsigned int)h) << 16);
}
__device__ __forceinline__ u16 f2bf(float f) {
  unsigned int u = __float_as_uint(f);
  unsigned int lsb = (u >> 16) & 1u;
  u += 0x7fffu + lsb;   // RNE
  return (u16)(u >> 16);
}

// ===========================================================================
// MFMA fast path
// ===========================================================================

// x fp32 -> bf16 into A_x[N][128]; blocks 0..199 also build the 4096-bucket
// histogram of dst>>5 (8000 edges each) via LDS + global flush.
__global__ __launch_bounds__(256) void convert_hist_k(const float* __restrict__ x,
                                                      const int* __restrict__ ei,
                                                      u16* __restrict__ Ax,
                                                      int* __restrict__ gh) {
  __shared__ int h[NBKT];
  int t = blockIdx.x * 256 + threadIdx.x;
  int row = t >> 5;
  int c = (t & 31) * 4;
  float4 v = *(const float4*)(x + (size_t)row * DIM + c);
  ushort4 o;
  o.x = f2bf(v.x); o.y = f2bf(v.y); o.z = f2bf(v.z); o.w = f2bf(v.w);
  *(ushort4*)(Ax + (size_t)row * DIM + c) = o;

  if (blockIdx.x < NBLK_BIN) {
    for (int i = threadIdx.x; i < NBKT; i += 256) h[i] = 0;
    __syncthreads();
    int e0 = blockIdx.x * EPB;
    for (int i = threadIdx.x; i < EPB; i += 256)
      atomicAdd(&h[ei[NE + e0 + i] >> 5], 1);
    __syncthreads();
    for (int i = threadIdx.x; i < NBKT; i += 256)
      if (h[i]) atomicAdd(&gh[i], h[i]);
  }
}

// Block 0: exclusive scan of 4096 bucket counts (4 per thread).
// Blocks 1..32: Wt[n][k] bf16 transpose (k<128 -> Wr[k][n]; else Wl[k-128][n]).
__global__ __launch_bounds__(1024) void scan_wt_k(const int* __restrict__ gh,
                                                  int* __restrict__ base,
                                                  int* __restrict__ cur,
                                                  const float* __restrict__ Wl,
                                                  const float* __restrict__ Wr,
                                                  u16* __restrict__ Wt) {
  __shared__ int p[1024];
  if (blockIdx.x == 0) {
    int t = threadIdx.x;
    int v0 = gh[4 * t], v1 = gh[4 * t + 1], v2 = gh[4 * t + 2], v3 = gh[4 * t + 3];
    int s = v0 + v1 + v2 + v3;
    p[t] = s;
    __syncthreads();
    for (int off = 1; off < 1024; off <<= 1) {
      int add = (t >= off) ? p[t - off] : 0;
      __syncthreads();
      p[t] += add;
      __syncthreads();
    }
    int e = p[t] - s;   // exclusive prefix at 4t
    base[4 * t] = e;              cur[4 * t] = e;
    base[4 * t + 1] = e + v0;     cur[4 * t + 1] = e + v0;
    base[4 * t + 2] = e + v0 + v1;     cur[4 * t + 2] = e + v0 + v1;
    base[4 * t + 3] = e + v0 + v1 + v2; cur[4 * t + 3] = e + v0 + v1 + v2;
    if (t == 1023) base[NBKT] = p[t];   // = NE
  } else {
    int idx = (blockIdx.x - 1) * 1024 + threadIdx.x;   // 32768 = 128*256
    int n = idx >> 8;
    int k = idx & 255;
    float v = (k < 128) ? Wr[(size_t)k * DIM + n] : Wl[(size_t)(k - 128) * DIM + n];
    Wt[(size_t)n * 256 + k] = f2bf(v);
  }
}

// Bin edges into bucket-contiguous regions as packed 4B records:
// rec = (dst&31)<<17 | src   (src < 2^17)
__global__ __launch_bounds__(256) void scatter_bin_k(const int* __restrict__ ei,
                                                     int* __restrict__ cur,
                                                     int* __restrict__ binned) {
  __shared__ int h[NBKT];
  __shared__ int bbase[NBKT];
  for (int i = threadIdx.x; i < NBKT; i += 256) h[i] = 0;
  __syncthreads();
  int e0 = blockIdx.x * EPB;
  for (int i = threadIdx.x; i < EPB; i += 256)
    atomicAdd(&h[ei[NE + e0 + i] >> 5], 1);
  __syncthreads();
  for (int i = threadIdx.x; i < NBKT; i += 256) {
    int c = h[i];
    bbase[i] = c ? atomicAdd(&cur[i], c) : 0;
    h[i] = 0;   // reuse as local cursor
  }
  __syncthreads();
  for (int i = threadIdx.x; i < EPB; i += 256) {
    int src = ei[e0 + i];
    int dst = ei[NE + e0 + i];
    int b = dst >> 5;
    int l = atomicAdd(&h[b], 1);
    binned[bbase[b] + l] = ((dst & 31) << 17) | src;
  }
}

// One block per 32-node bucket: stage records in LDS, counting-sort, then
// wave-per-node gather-aggregate from A_x into A_g. LDS ~8.8KB, VGPR ~12
// -> 8 blocks/CU; grid 3125 (12.2/CU) keeps CUs full.
__global__ __launch_bounds__(256) void aggB_k(const int* __restrict__ base,
                                              const int* __restrict__ binned,
                                              const u16* __restrict__ Ax,
                                              u16* __restrict__ Ag) {
  __shared__ int recS[BK_CAP];
  __shared__ int srcS[BK_CAP];
  __shared__ int hist[32];
  __shared__ int off[32];
  __shared__ int cur[32];
  const int b = blockIdx.x;
  const int lo = base[b];
  int cnt = base[b + 1] - lo;
  if (cnt > BK_CAP) cnt = BK_CAP;   // statistical impossibility; OOB guard

  if (threadIdx.x < 32) hist[threadIdx.x] = 0;
  __syncthreads();
  for (int i = threadIdx.x; i < cnt; i += 256) {
    int rec = binned[lo + i];
    recS[i] = rec;
    atomicAdd(&hist[rec >> 17], 1);
  }
  __syncthreads();
  if (threadIdx.x < 32) off[threadIdx.x] = hist[threadIdx.x];
  __syncthreads();
  for (int st = 1; st < 32; st <<= 1) {
    int add = 0;
    if (threadIdx.x < 32 && threadIdx.x >= st) add = off[threadIdx.x - st];
    __syncthreads();
    if (threadIdx.x < 32) off[threadIdx.x] += add;
    __syncthreads();
  }
  if (threadIdx.x < 32) cur[threadIdx.x] = off[threadIdx.x] - hist[threadIdx.x];
  __syncthreads();
  for (int i = threadIdx.x; i < cnt; i += 256) {
    int rec = recS[i];
    int l = atomicAdd(&cur[rec >> 17], 1);
    srcS[l] = rec & 0x1FFFF;
  }
  __syncthreads();

  const int wid = threadIdx.x >> 6;
  const int lane = threadIdx.x & 63;
  const int node0 = b * 32;
  for (int ln = wid; ln < 32; ln += 4) {
    int node = node0 + ln;
    int d = hist[ln];
    int e1 = off[ln];
    int j = e1 - d;
    float ax = 0.f, ay = 0.f;
    for (; j + 4 <= e1; j += 4) {
      int s0 = srcS[j], s1 = srcS[j + 1], s2 = srcS[j + 2], s3 = srcS[j + 3];
      unsigned u0 = *(const unsigned*)(Ax + (size_t)s0 * DIM + lane * 2);
      unsigned u1 = *(const unsigned*)(Ax + (size_t)s1 * DIM + lane * 2);
      unsigned u2 = *(const unsigned*)(Ax + (size_t)s2 * DIM + lane * 2);
      unsigned u3 = *(const unsigned*)(Ax + (size_t)s3 * DIM + lane * 2);
      ax += bf2f((u16)u0) + bf2f((u16)u1) + bf2f((u16)u2) + bf2f((u16)u3);
      ay += bf2f((u16)(u0 >> 16)) + bf2f((u16)(u1 >> 16)) +
            bf2f((u16)(u2 >> 16)) + bf2f((u16)(u3 >> 16));
    }
    for (; j < e1; ++j) {
      unsigned u0 = *(const unsigned*)(Ax + (size_t)srcS[j] * DIM + lane * 2);
      ax += bf2f((u16)u0);
      ay += bf2f((u16)(u0 >> 16));
    }
    float scale = 1.0f / fmaxf((float)d, 1.0f);
    unsigned p = (unsigned)f2bf(ax * scale) | ((unsigned)f2bf(ay * scale) << 16);
    *(unsigned*)(Ag + (size_t)node * DIM + lane * 2) = p;
  }
}

// Fused GEMM: out[M][128] = [Ax | Ag][M][256](bf16) @ Wc[256][128] + b.
// Persistent loop with double-buffered A-fragment prefetch: load tile t+1's
// 8 dwordx4 frags before the 16 MFMAs of tile t. k-frag s<4 from Ax, s>=4
// from Ag (k = s*32 + q*8 + j).
__global__ __launch_bounds__(256) void gemm_mfma(const u16* __restrict__ Ax,
                                                 const u16* __restrict__ Ag,
                                                 const u16* __restrict__ Wt,
                                                 const float* __restrict__ bias,
                                                 float* __restrict__ out) {
  const int wave = threadIdx.x >> 6;
  const int lane = threadIdx.x & 63;
  const int m = lane & 15;
  const int q = lane >> 4;
  const int n0 = wave * 32;

  bf16x8 Bf[2][8];
#pragma unroll
  for (int t = 0; t < 2; ++t) {
    const u16* bp = Wt + (size_t)(n0 + t * 16 + m) * 256 + q * 8;
#pragma unroll
    for (int s = 0; s < 8; ++s) Bf[t][s] = *(const bf16x8*)(bp + s * 32);
  }
  const float b0 = bias[n0 + m];
  const float b1 = bias[n0 + 16 + m];

  const int NT = N_NODES / 16;   // 6250
  int rt = blockIdx.x;
  bf16x8 Ac[8];
  {
    const u16* apx = Ax + (size_t)(rt * 16 + m) * DIM + q * 8;
    const u16* apg = Ag + (size_t)(rt * 16 + m) * DIM + q * 8;
#pragma unroll
    for (int s = 0; s < 4; ++s) Ac[s] = *(const bf16x8*)(apx + s * 32);
#pragma unroll
    for (int s = 4; s < 8; ++s) Ac[s] = *(const bf16x8*)(apg + (s - 4) * 32);
  }
  while (true) {
    int rn = rt + gridDim.x;
    bf16x8 An[8];
    if (rn < NT) {
      const u16* apx = Ax + (size_t)(rn * 16 + m) * DIM + q * 8;
      const u16* apg = Ag + (size_t)(rn * 16 + m) * DIM + q * 8;
#pragma unroll
      for (int s = 0; s < 4; ++s) An[s] = *(const bf16x8*)(apx + s * 32);
#pragma unroll
      for (int s = 4; s < 8; ++s) An[s] = *(const bf16x8*)(apg + (s - 4) * 32);
    }
    f32x4 acc0 = {0.f, 0.f, 0.f, 0.f};
    f32x4 acc1 = {0.f, 0.f, 0.f, 0.f};
#pragma unroll
    for (int s = 0; s < 8; ++s) {
      acc0 = __builtin_amdgcn_mfma_f32_16x16x32_bf16(Ac[s], Bf[0][s], acc0, 0, 0, 0);
      acc1 = __builtin_amdgcn_mfma_f32_16x16x32_bf16(Ac[s], Bf[1][s], acc1, 0, 0, 0);
    }
    float* o = out + (size_t)(rt * 16 + q * 4) * DIM + n0 + m;
#pragma unroll
    for (int r = 0; r < 4; ++r) {
      o[(size_t)r * DIM] = acc0[r] + b0;
      o[(size_t)r * DIM + 16] = acc1[r] + b1;
    }
    if (rn >= NT) break;
#pragma unroll
    for (int s = 0; s < 8; ++s) Ac[s] = An[s];
    rt = rn;
  }
}

// ===========================================================================
// fp32 fallback path (round-3 proven) — only if ws too small for fast path
// ===========================================================================
__global__ __launch_bounds__(256) void hist_k(const int* __restrict__ ei,
                                              int* __restrict__ deg) {
  int e = blockIdx.x * 256 + threadIdx.x;
  if (e < NE) atomicAdd(&deg[ei[NE + e]], 1);
}

__global__ __launch_bounds__(512) void scan_sum_k(const int* __restrict__ deg,
                                                  int* __restrict__ partials) {
  __shared__ int s[CHUNK];
  int i = blockIdx.x * CHUNK + threadIdx.x;
  s[threadIdx.x] = (i < N_NODES) ? deg[i] : 0;
  __syncthreads();
  for (int off = 256; off > 0; off >>= 1) {
    if (threadIdx.x < off) s[threadIdx.x] += s[threadIdx.x + off];
    __syncthreads();
  }
  if (threadIdx.x == 0) partials[blockIdx.x] = s[0];
}

__global__ __launch_bounds__(256) void scan_part_k(int* __restrict__ partials) {
  __shared__ int s[256];
  int t = threadIdx.x;
  int v = (t < NCHUNK) ? partials[t] : 0;
  s[t] = v;
  __syncthreads();
  for (int off = 1; off < 256; off <<= 1) {
    int add = (t >= off) ? s[t - off] : 0;
    __syncthreads();
    s[t] += add;
    __syncthreads();
  }
  if (t < NCHUNK) partials[t] = s[t] - v;
}

__global__ __launch_bounds__(512) void scan_out_k(const int* __restrict__ deg,
                                                  const int* __restrict__ partials,
                                                  int* __restrict__ offsets,
                                                  int* __restrict__ cursor) {
  __shared__ int s[CHUNK];
  int t = threadIdx.x;
  int i = blockIdx.x * CHUNK + t;
  int v = (i < N_NODES) ? deg[i] : 0;
  s[t] = v;
  __syncthreads();
  for (int off = 1; off < CHUNK; off <<= 1) {
    int add = (t >= off) ? s[t - off] : 0;
    __syncthreads();
    s[t] += add;
    __syncthreads();
  }
  if (i < N_NODES) {
    int excl = partials[blockIdx.x] + s[t] - v;
    offsets[i] = excl;
    cursor[i] = excl;
  }
  if (i == 0) offsets[N_NODES] = NE;
}

__global__ __launch_bounds__(256) void fill_k(const int* __restrict__ ei,
                                              int* __restrict__ cursor,
                                              int* __restrict__ csr) {
  int e = blockIdx.x * 256 + threadIdx.x;
  if (e < NE) {
    int dst = ei[NE + e];
    int pos = atomicAdd(&cursor[dst], 1);
    csr[pos] = ei[e];
  }
}

__global__ __launch_bounds__(256) void agg_f32_k(const int* __restrict__ offsets,
                                                 const int* __restrict__ csr,
                                                 const float* __restrict__ x,
                                                 float* __restrict__ agg) {
  int node = blockIdx.x * 4 + (threadIdx.x >> 6);
  int lane = threadIdx.x & 63;
  int beg = offsets[node], end = offsets[node + 1];
  float ax = 0.f, ay = 0.f;
  int i = beg;
  for (; i + 4 <= end; i += 4) {
    int s0 = csr[i], s1 = csr[i + 1], s2 = csr[i + 2], s3 = csr[i + 3];
    float2 v0 = *(const float2*)(x + (size_t)s0 * DIM + lane * 2);
    float2 v1 = *(const float2*)(x + (size_t)s1 * DIM + lane * 2);
    float2 v2 = *(const float2*)(x + (size_t)s2 * DIM + lane * 2);
    float2 v3 = *(const float2*)(x + (size_t)s3 * DIM + lane * 2);
    ax += v0.x + v1.x + v2.x + v3.x;
    ay += v0.y + v1.y + v2.y + v3.y;
  }
  for (; i < end; ++i) {
    float2 v0 = *(const float2*)(x + (size_t)csr[i] * DIM + lane * 2);
    ax += v0.x;
    ay += v0.y;
  }
  float scale = 1.0f / fmaxf((float)(end - beg), 1.0f);
  float2 r;
  r.x = ax * scale;
  r.y = ay * scale;
  *(float2*)(agg + (size_t)node * DIM + lane * 2) = r;
}

__global__ __launch_bounds__(256) void gemm_xw(const float* __restrict__ x,
                                               const float* __restrict__ W,
                                               const float* __restrict__ b,
                                               float* __restrict__ out) {
  __shared__ float Ws[DIM * DIM];
  for (int i = threadIdx.x; i < DIM * DIM; i += 256) Ws[i] = W[i];
  __syncthreads();
  const int c = threadIdx.x & 127;
  const int half = threadIdx.x >> 7;
  const float bias = b[c];
  for (int tile = blockIdx.x; tile < NTILES; tile += gridDim.x) {
    const int row0 = tile * 8 + half * 4;
    const float* r = x + (size_t)row0 * DIM;
    float a0 = 0.f, a1 = 0.f, a2 = 0.f, a3 = 0.f;
#pragma unroll 8
    for (int k4 = 0; k4 < 32; ++k4) {
      float4 p0 = *(const float4*)(r + 0 * DIM + k4 * 4);
      float4 p1 = *(const float4*)(r + 1 * DIM + k4 * 4);
      float4 p2 = *(const float4*)(r + 2 * DIM + k4 * 4);
      float4 p3 = *(const float4*)(r + 3 * DIM + k4 * 4);
      const float* wp = &Ws[k4 * 4 * DIM + c];
      float w0 = wp[0 * DIM], w1 = wp[1 * DIM], w2 = wp[2 * DIM], w3 = wp[3 * DIM];
      a0 += p0.x * w0 + p0.y * w1 + p0.z * w2 + p0.w * w3;
      a1 += p1.x * w0 + p1.y * w1 + p1.z * w2 + p1.w * w3;
      a2 += p2.x * w0 + p2.y * w1 + p2.z * w2 + p2.w * w3;
      a3 += p3.x * w0 + p3.y * w1 + p3.z * w2 + p3.w * w3;
    }
    out[(size_t)(row0 + 0) * DIM + c] = a0 + bias;
    out[(size_t)(row0 + 1) * DIM + c] = a1 + bias;
    out[(size_t)(row0 + 2) * DIM + c] = a2 + bias;
    out[(size_t)(row0 + 3) * DIM + c] = a3 + bias;
  }
}

__global__ __launch_bounds__(256) void gemm_aw(const float* __restrict__ agg,
                                               const float* __restrict__ W,
                                               float* __restrict__ out) {
  __shared__ float Ws[DIM * DIM];
  for (int i = threadIdx.x; i < DIM * DIM; i += 256) Ws[i] = W[i];
  __syncthreads();
  const int c = threadIdx.x & 127;
  const int half = threadIdx.x >> 7;
  for (int tile = blockIdx.x; tile < NTILES; tile += gridDim.x) {
    const int row0 = tile * 8 + half * 4;
    const float* r = agg + (size_t)row0 * DIM;
    float a0 = 0.f, a1 = 0.f, a2 = 0.f, a3 = 0.f;
#pragma unroll 8
    for (int k4 = 0; k4 < 32; ++k4) {
      float4 p0 = *(const float4*)(r + 0 * DIM + k4 * 4);
      float4 p1 = *(const float4*)(r + 1 * DIM + k4 * 4);
      float4 p2 = *(const float4*)(r + 2 * DIM + k4 * 4);
      float4 p3 = *(const float4*)(r + 3 * DIM + k4 * 4);
      const float* wp = &Ws[k4 * 4 * DIM + c];
      float w0 = wp[0 * DIM], w1 = wp[1 * DIM], w2 = wp[2 * DIM], w3 = wp[3 * DIM];
      a0 += p0.x * w0 + p0.y * w1 + p0.z * w2 + p0.w * w3;
      a1 += p1.x * w0 + p1.y * w1 + p1.z * w2 + p1.w * w3;
      a2 += p2.x * w0 + p2.y * w1 + p2.z * w2 + p2.w * w3;
      a3 += p3.x * w0 + p3.y * w1 + p3.z * w2 + p3.w * w3;
    }
    out[(size_t)(row0 + 0) * DIM + c] += a0;
    out[(size_t)(row0 + 1) * DIM + c] += a1;
    out[(size_t)(row0 + 2) * DIM + c] += a2;
    out[(size_t)(row0 + 3) * DIM + c] += a3;
  }
}

extern "C" void kernel_launch(void* const* d_in, const int* in_sizes, int n_in,
                              void* d_out, int out_size, void* d_ws, size_t ws_size,
                              hipStream_t stream) {
  const float* x  = (const float*)d_in[0];
  const int*   ei = (const int*)d_in[1];
  const float* Wl = (const float*)d_in[2];
  const float* bl = (const float*)d_in[3];
  const float* Wr = (const float*)d_in[4];
  float* out = (float*)d_out;

  // --- fast-path workspace layout ---
  u16* Ax       = (u16*)d_ws;                   // [N][128] bf16 = 25.6 MB
  u16* Ag       = Ax + (size_t)N_NODES * DIM;   // [N][128] bf16 = 25.6 MB
  u16* Wt       = Ag + (size_t)N_NODES * DIM;   // [128][256] bf16 = 64 KB
  int* binned   = (int*)(Wt + 128 * 256);       // [NE] 4B packed = 6.4 MB
  int* bktHist  = binned + NE;                  // [4096]
  int* bktBase  = bktHist + NBKT;               // [4097]
  int* bktCur   = bktBase + NBKT + 1;           // [4096]
  size_t needed = (size_t)N_NODES * DIM * 2 * 2 + 65536 + (size_t)NE * 4 +
                  (NBKT + NBKT + 1 + NBKT) * 4;

  if (ws_size >= needed) {
    hipMemsetAsync(bktHist, 0, NBKT * sizeof(int), stream);
    hipLaunchKernelGGL(convert_hist_k, dim3(12500), dim3(256), 0, stream,
                       x, ei, Ax, bktHist);
    hipLaunchKernelGGL(scan_wt_k, dim3(33), dim3(1024), 0, stream,
                       bktHist, bktBase, bktCur, Wl, Wr, Wt);
    hipLaunchKernelGGL(scatter_bin_k, dim3(NBLK_BIN), dim3(256), 0, stream,
                       ei, bktCur, binned);
    hipLaunchKernelGGL(aggB_k, dim3(NB32), dim3(256), 0, stream,
                       bktBase, binned, Ax, Ag);
    hipLaunchKernelGGL(gemm_mfma, dim3(1250), dim3(256), 0, stream,
                       Ax, Ag, Wt, bl, out);
  } else {
    // fp32 CSR fallback (round-3 layout)
    int* deg2      = (int*)d_ws;
    int* offsets2  = deg2 + N_NODES;
    int* partials2 = offsets2 + 100004;
    int* csr2      = partials2 + 256;
    float* agg     = (float*)(csr2 + NE);
    hipMemsetAsync(deg2, 0, (size_t)N_NODES * sizeof(int), stream);
    hipLaunchKernelGGL(hist_k, dim3((NE + 255) / 256), dim3(256), 0, stream, ei, deg2);
    hipLaunchKernelGGL(scan_sum_k, dim3(NCHUNK), dim3(CHUNK), 0, stream, deg2, partials2);
    hipLaunchKernelGGL(scan_part_k, dim3(1), dim3(256), 0, stream, partials2);
    hipLaunchKernelGGL(scan_out_k, dim3(NCHUNK), dim3(CHUNK), 0, stream,
                       deg2, partials2, offsets2, deg2);
    hipLaunchKernelGGL(fill_k, dim3((NE + 255) / 256), dim3(256), 0, stream,
                       ei, deg2, csr2);
    hipLaunchKernelGGL(agg_f32_k, dim3(N_NODES / 4), dim3(256), 0, stream,
                       offsets2, csr2, x, agg);
    hipLaunchKernelGGL(gemm_xw, dim3(GEMM_BLOCKS), dim3(256), 0, stream,
                       x, Wr, bl, out);
    hipLaunchKernelGGL(gemm_aw, dim3(GEMM_BLOCKS), dim3(256), 0, stream,
                       agg, Wl, out);
  }
}